// Round 2
// baseline (775.436 us; speedup 1.0000x reference)
//
#include <hip/hip_runtime.h>

typedef unsigned short u16;
typedef __attribute__((ext_vector_type(8))) short short8;
typedef __attribute__((ext_vector_type(4))) unsigned short ushort4v;
typedef __attribute__((ext_vector_type(8))) unsigned short ushort8v;
typedef __attribute__((ext_vector_type(4))) float f32x4;

#define MFMA_16x16x32(a, b, c) __builtin_amdgcn_mfma_f32_16x16x32_bf16(a, b, c, 0, 0, 0)

__device__ __forceinline__ u16 f2bf(float f) {
    unsigned int u = __float_as_uint(f);
    u += 0x7fffu + ((u >> 16) & 1u);
    return (u16)(u >> 16);
}

// ---------------- elementwise cast fp32 -> bf16 (8 elems/thread) ----------------
__global__ __launch_bounds__(256) void k_cast(const float* __restrict__ in, u16* __restrict__ out) {
    long i = ((long)blockIdx.x * 256 + threadIdx.x) * 8;
    f32x4 a = *(const f32x4*)(in + i);
    f32x4 b = *(const f32x4*)(in + i + 4);
    ushort8v o;
    o[0] = f2bf(a[0]); o[1] = f2bf(a[1]); o[2] = f2bf(a[2]); o[3] = f2bf(a[3]);
    o[4] = f2bf(b[0]); o[5] = f2bf(b[1]); o[6] = f2bf(b[2]); o[7] = f2bf(b[3]);
    *(ushort8v*)(out + i) = o;
}

// ---------------- transpose + cast: in fp32 [R][C] (+z*ibs) -> out bf16 [C][R] (+z*obs) ----------------
__global__ __launch_bounds__(256) void k_tcast(const float* __restrict__ in, u16* __restrict__ out,
                                               int R, int C, long ibs, long obs) {
    __shared__ float tile[32][33];
    const int t = threadIdx.x;
    const int tx = t & 31, ty = t >> 5;
    const long r0 = (long)blockIdx.y * 32, c0 = (long)blockIdx.x * 32;
    const float* ip = in + (long)blockIdx.z * ibs;
    u16* op = out + (long)blockIdx.z * obs;
#pragma unroll
    for (int i = 0; i < 4; i++)
        tile[ty + 8 * i][tx] = ip[(r0 + ty + 8 * i) * C + c0 + tx];
    __syncthreads();
#pragma unroll
    for (int i = 0; i < 4; i++)
        op[(c0 + ty + 8 * i) * R + r0 + tx] = f2bf(tile[tx][ty + 8 * i]);
}

// ---------------- GEMM: C[M][N] = A[M][K] * B, with Bt[N][K]; A,Bt bf16, C fp32 ----------------
// 128x128 tile, BK=32, 4 waves (2x2 of 64x64), mfma 16x16x32 bf16.
__global__ __launch_bounds__(256) void k_gemm(const u16* __restrict__ A, const u16* __restrict__ Bt,
                                              float* __restrict__ C, int M, int N, int K) {
    (void)M;
    __shared__ u16 As[128 * 40];
    __shared__ u16 Bs[128 * 40];
    const int t = threadIdx.x;
    const int lane = t & 63, wave = t >> 6;
    const long m0 = (long)blockIdx.y * 128, n0 = (long)blockIdx.x * 128;
    const int wm = (wave >> 1) * 64, wn = (wave & 1) * 64;
    const int srow = t >> 2, scol = (t & 3) * 8;
    const u16* Ap = A + (m0 + srow) * K + scol;
    const u16* Bp = Bt + (n0 + srow) * K + scol;
    const int fr = lane & 15, fg = (lane >> 4) * 8;
    const f32x4 z = {0.f, 0.f, 0.f, 0.f};
    f32x4 acc[4][4];
#pragma unroll
    for (int i = 0; i < 4; i++)
#pragma unroll
        for (int j = 0; j < 4; j++) acc[i][j] = z;
    for (int k0 = 0; k0 < K; k0 += 32) {
        short8 a0 = *(const short8*)(Ap + k0);
        short8 a1 = *(const short8*)(Ap + (long)64 * K + k0);
        short8 b0 = *(const short8*)(Bp + k0);
        short8 b1 = *(const short8*)(Bp + (long)64 * K + k0);
        __syncthreads();
        *(short8*)&As[srow * 40 + scol] = a0;
        *(short8*)&As[(srow + 64) * 40 + scol] = a1;
        *(short8*)&Bs[srow * 40 + scol] = b0;
        *(short8*)&Bs[(srow + 64) * 40 + scol] = b1;
        __syncthreads();
        short8 af[4], bf[4];
#pragma unroll
        for (int i = 0; i < 4; i++) {
            af[i] = *(const short8*)&As[(wm + i * 16 + fr) * 40 + fg];
            bf[i] = *(const short8*)&Bs[(wn + i * 16 + fr) * 40 + fg];
        }
#pragma unroll
        for (int i = 0; i < 4; i++)
#pragma unroll
            for (int j = 0; j < 4; j++)
                acc[i][j] = MFMA_16x16x32(af[i], bf[j], acc[i][j]);
    }
    const int cr = (lane >> 4) * 4, cc = lane & 15;
#pragma unroll
    for (int i = 0; i < 4; i++)
#pragma unroll
        for (int j = 0; j < 4; j++)
#pragma unroll
            for (int r = 0; r < 4; r++)
                C[(m0 + wm + i * 16 + cr + r) * N + (n0 + wn + j * 16 + cc)] = acc[i][j][r];
}

// ---------------- LayerNorm over 2048 cols (+ optional RoPE) -> bf16 [B,H,Srows,128] ----------------
__global__ __launch_bounds__(256) void k_ln(const float* __restrict__ in, const float* __restrict__ w,
                                            const float* __restrict__ bia, const float* __restrict__ freqs,
                                            u16* __restrict__ out, int Srows, float eps, int do_rope) {
    const int row = blockIdx.x;
    const int bi = row / Srows, s = row - bi * Srows;
    const int t = threadIdx.x;
    const long base = (long)row * 2048 + t * 8;
    f32x4 v0 = *(const f32x4*)(in + base);
    f32x4 v1 = *(const f32x4*)(in + base + 4);
    float sum = 0.f, sq = 0.f;
#pragma unroll
    for (int r = 0; r < 4; r++) {
        sum += v0[r] + v1[r];
        sq += v0[r] * v0[r] + v1[r] * v1[r];
    }
#pragma unroll
    for (int off = 32; off >= 1; off >>= 1) {
        sum += __shfl_xor(sum, off);
        sq += __shfl_xor(sq, off);
    }
    __shared__ float red[8];
    const int wv = t >> 6, lane = t & 63;
    if (lane == 0) { red[wv] = sum; red[4 + wv] = sq; }
    __syncthreads();
    sum = red[0] + red[1] + red[2] + red[3];
    sq  = red[4] + red[5] + red[6] + red[7];
    const float mu = sum * (1.f / 2048.f);
    const float rstd = rsqrtf(sq * (1.f / 2048.f) - mu * mu + eps);
    const int c0 = t * 8;
    f32x4 w0 = *(const f32x4*)(w + c0), w1 = *(const f32x4*)(w + c0 + 4);
    f32x4 b0 = *(const f32x4*)(bia + c0), b1 = *(const f32x4*)(bia + c0 + 4);
    float nv[8];
#pragma unroll
    for (int r = 0; r < 4; r++) {
        nv[r]     = (v0[r] - mu) * rstd * w0[r] + b0[r];
        nv[4 + r] = (v1[r] - mu) * rstd * w1[r] + b1[r];
    }
    if (do_rope) {
        const float* fp = freqs + ((long)s * 64 + ((c0 & 127) >> 1)) * 2;
        f32x4 f0 = *(const f32x4*)(fp), f1 = *(const f32x4*)(fp + 4);
        float t0, t1;
        t0 = nv[0]; t1 = nv[1]; nv[0] = t0 * f0[0] - t1 * f0[1]; nv[1] = t0 * f0[1] + t1 * f0[0];
        t0 = nv[2]; t1 = nv[3]; nv[2] = t0 * f0[2] - t1 * f0[3]; nv[3] = t0 * f0[3] + t1 * f0[2];
        t0 = nv[4]; t1 = nv[5]; nv[4] = t0 * f1[0] - t1 * f1[1]; nv[5] = t0 * f1[1] + t1 * f1[0];
        t0 = nv[6]; t1 = nv[7]; nv[6] = t0 * f1[2] - t1 * f1[3]; nv[7] = t0 * f1[3] + t1 * f1[2];
    }
    const int h = c0 >> 7;
    ushort8v o;
#pragma unroll
    for (int r = 0; r < 8; r++) o[r] = f2bf(nv[r]);
    *(ushort8v*)(out + (((long)bi * 16 + h) * Srows + s) * 128 + (c0 & 127)) = o;
}

// ---------------- fused dual flash attention ----------------
// Q,K: [B,H,S,128] bf16; Vt: [B,H,128,S]; Yk: [B,H,512,128]; Yvt: [B,H,128,512]
// out: [B,S,H*128] bf16.  Block: 256 thr = 4 waves, each wave 16 q-rows; 32-key tiles.
__global__ __launch_bounds__(256) void k_attn(const u16* __restrict__ Q, const u16* __restrict__ Kg,
                                              const u16* __restrict__ Vt, const u16* __restrict__ Yk,
                                              const u16* __restrict__ Yvt, const float* __restrict__ gate,
                                              u16* __restrict__ Out) {
    __shared__ u16 Ks[32 * 136];
    __shared__ u16 Vs[128 * 40];
    __shared__ u16 Ps[4][16 * 40];
    const int t = threadIdx.x, lane = t & 63, wave = t >> 6;
    const int h = blockIdx.y, b = blockIdx.z;
    const int q0 = blockIdx.x * 64 + wave * 16;
    const long bh = (long)b * 16 + h;
    const int fr = lane & 15;
    const int g = lane >> 4;
    const int fg8 = g * 8;
    const float scale = 0.08838834764831845f;  // 1/sqrt(128)
    const f32x4 z = {0.f, 0.f, 0.f, 0.f};

    // Q fragments (B-operand: col = q-row = fr, k = d)
    const u16* qp = Q + (bh * 2048 + q0 + fr) * 128;
    short8 qf[4];
#pragma unroll
    for (int ks = 0; ks < 4; ks++) qf[ks] = *(const short8*)(qp + fg8 + ks * 32);

    f32x4 o1[8], o2[8];

    auto flash = [&](const u16* kp, const u16* vp, int L, int vstride, f32x4* oout) {
        float m = -3.0e38f, l = 0.f;
        f32x4 oacc[8];
#pragma unroll
        for (int i = 0; i < 8; i++) oacc[i] = z;
        for (int kb = 0; kb < L; kb += 32) {
            __syncthreads();
#pragma unroll
            for (int i = 0; i < 2; i++) {  // stage K tile 32x128
                int idx = t + 256 * i;
                int r = idx >> 4, c = (idx & 15) * 8;
                *(short8*)&Ks[r * 136 + c] = *(const short8*)(kp + (long)(kb + r) * 128 + c);
            }
#pragma unroll
            for (int i = 0; i < 2; i++) {  // stage Vt tile 128x32
                int idx = t + 256 * i;
                int r = idx >> 2, c = (idx & 3) * 8;
                *(short8*)&Vs[r * 40 + c] = *(const short8*)(vp + (long)r * vstride + kb + c);
            }
            __syncthreads();
            // S^T = K * Q^T : col=q (fr), row=key_local (4g+r)
            f32x4 c0 = z, c1 = z;
#pragma unroll
            for (int ks = 0; ks < 4; ks++) {
                short8 k0f = *(const short8*)&Ks[fr * 136 + fg8 + ks * 32];
                short8 k1f = *(const short8*)&Ks[(16 + fr) * 136 + fg8 + ks * 32];
                c0 = MFMA_16x16x32(k0f, qf[ks], c0);
                c1 = MFMA_16x16x32(k1f, qf[ks], c1);
            }
            float s[8];
#pragma unroll
            for (int r = 0; r < 4; r++) { s[r] = c0[r] * scale; s[4 + r] = c1[r] * scale; }
            float tmax = s[0];
#pragma unroll
            for (int r = 1; r < 8; r++) tmax = fmaxf(tmax, s[r]);
            tmax = fmaxf(tmax, __shfl_xor(tmax, 16));
            tmax = fmaxf(tmax, __shfl_xor(tmax, 32));
            if (!__all(tmax <= m + 8.f)) {  // defer-max rescale
                float mn = fmaxf(m, tmax);
                float corr = __expf(m - mn);
#pragma unroll
                for (int i = 0; i < 8; i++) oacc[i] *= corr;
                l *= corr;
                m = mn;
            }
            float p[8], ts = 0.f;
#pragma unroll
            for (int r = 0; r < 8; r++) { p[r] = __expf(s[r] - m); ts += p[r]; }
            ts += __shfl_xor(ts, 16);
            ts += __shfl_xor(ts, 32);
            l += ts;
            ushort4v pk0, pk1;
#pragma unroll
            for (int r = 0; r < 4; r++) { pk0[r] = f2bf(p[r]); pk1[r] = f2bf(p[4 + r]); }
            // P stored [q][key] so PV B-frag is a single contiguous b128 read
            *(ushort4v*)&Ps[wave][fr * 40 + g * 4] = pk0;
            *(ushort4v*)&Ps[wave][fr * 40 + 16 + g * 4] = pk1;
            short8 pf = *(const short8*)&Ps[wave][fr * 40 + fg8];
#pragma unroll
            for (int dt = 0; dt < 8; dt++) {  // O^T += V^T * P^T
                short8 vf = *(const short8*)&Vs[(dt * 16 + fr) * 40 + fg8];
                oacc[dt] = MFMA_16x16x32(vf, pf, oacc[dt]);
            }
        }
        float inv = 1.f / l;
#pragma unroll
        for (int i = 0; i < 8; i++) oout[i] = oacc[i] * inv;
    };

    flash(Kg + bh * 2048 * 128, Vt + bh * 128 * 2048, 2048, 2048, o1);
    flash(Yk + bh * 512 * 128, Yvt + bh * 128 * 512, 512, 512, o2);

    const float tg = tanhf(gate[h]);
    u16* op = Out + ((long)b * 2048 + q0 + fr) * 2048 + h * 128;
#pragma unroll
    for (int dt = 0; dt < 8; dt++) {
        ushort4v w4;
#pragma unroll
        for (int r = 0; r < 4; r++) w4[r] = f2bf(o1[dt][r] + tg * o2[dt][r]);
        *(ushort4v*)(op + dt * 16 + g * 4) = w4;
    }
}

extern "C" void kernel_launch(void* const* d_in, const int* in_sizes, int n_in,
                              void* d_out, int out_size, void* d_ws, size_t ws_size,
                              hipStream_t stream) {
    (void)in_sizes; (void)n_in; (void)out_size; (void)ws_size;
    const float* x     = (const float*)d_in[0];
    const float* freqs = (const float*)d_in[2];
    const float* y     = (const float*)d_in[3];
    const float* wq    = (const float*)d_in[5];
    const float* wk    = (const float*)d_in[6];
    const float* wv    = (const float*)d_in[7];
    const float* wo    = (const float*)d_in[8];
    const float* wky   = (const float*)d_in[9];
    const float* wvy   = (const float*)d_in[10];
    const float* gate  = (const float*)d_in[11];
    const float* qn_w  = (const float*)d_in[12];
    const float* qn_b  = (const float*)d_in[13];
    const float* kn_w  = (const float*)d_in[14];
    const float* kn_b  = (const float*)d_in[15];
    const float* kyn_w = (const float*)d_in[16];
    const float* kyn_b = (const float*)d_in[17];
    float* out = (float*)d_out;

    char* p = (char*)d_ws;
    u16* xb   = (u16*)p; p += 4096L * 2048 * 2;
    u16* yb   = (u16*)p; p += 1024L * 2048 * 2;
    u16* wT   = (u16*)p; p += 2048L * 2048 * 2;
    u16* qb   = (u16*)p; p += 4096L * 2048 * 2;
    u16* kbuf = (u16*)p; p += 4096L * 2048 * 2;
    u16* vtb  = (u16*)p; p += 4096L * 2048 * 2;
    u16* ykb  = (u16*)p; p += 1024L * 2048 * 2;
    u16* yvtb = (u16*)p; p += 1024L * 2048 * 2;
    u16* aob  = (u16*)p; p += 4096L * 2048 * 2;
    float* raw = out;  // d_out doubles as fp32 scratch (exactly 4096x2048 fp32)

    k_cast<<<dim3(4096), dim3(256), 0, stream>>>(x, xb);
    k_cast<<<dim3(1024), dim3(256), 0, stream>>>(y, yb);

    // Q path
    k_tcast<<<dim3(64, 64, 1), dim3(256), 0, stream>>>(wq, wT, 2048, 2048, 0, 0);
    k_gemm<<<dim3(16, 32), dim3(256), 0, stream>>>(xb, wT, raw, 4096, 2048, 2048);
    k_ln<<<dim3(4096), dim3(256), 0, stream>>>(raw, qn_w, qn_b, freqs, qb, 2048, 1e-5f, 1);
    // K path
    k_tcast<<<dim3(64, 64, 1), dim3(256), 0, stream>>>(wk, wT, 2048, 2048, 0, 0);
    k_gemm<<<dim3(16, 32), dim3(256), 0, stream>>>(xb, wT, raw, 4096, 2048, 2048);
    k_ln<<<dim3(4096), dim3(256), 0, stream>>>(raw, kn_w, kn_b, freqs, kbuf, 2048, 1e-5f, 1);
    // V path (transpose to [B,H,128,S])
    k_tcast<<<dim3(64, 64, 1), dim3(256), 0, stream>>>(wv, wT, 2048, 2048, 0, 0);
    k_gemm<<<dim3(16, 32), dim3(256), 0, stream>>>(xb, wT, raw, 4096, 2048, 2048);
    k_tcast<<<dim3(64, 64, 2), dim3(256), 0, stream>>>(raw, vtb, 2048, 2048, 2048L * 2048, 2048L * 2048);
    // yK path
    k_tcast<<<dim3(64, 64, 1), dim3(256), 0, stream>>>(wky, wT, 2048, 2048, 0, 0);
    k_gemm<<<dim3(16, 8), dim3(256), 0, stream>>>(yb, wT, raw, 1024, 2048, 2048);
    k_ln<<<dim3(1024), dim3(256), 0, stream>>>(raw, kyn_w, kyn_b, freqs, ykb, 512, 1e-6f, 0);
    // yV path (transpose to [B,H,128,512])
    k_tcast<<<dim3(64, 64, 1), dim3(256), 0, stream>>>(wvy, wT, 2048, 2048, 0, 0);
    k_gemm<<<dim3(16, 8), dim3(256), 0, stream>>>(yb, wT, raw, 1024, 2048, 2048);
    k_tcast<<<dim3(64, 16, 2), dim3(256), 0, stream>>>(raw, yvtb, 512, 2048, 512L * 2048, 2048L * 512);
    // fused dual attention
    k_attn<<<dim3(32, 16, 2), dim3(256), 0, stream>>>(qb, kbuf, vtb, ykb, yvtb, gate, aob);
    // output projection
    k_tcast<<<dim3(64, 64, 1), dim3(256), 0, stream>>>(wo, wT, 2048, 2048, 0, 0);
    k_gemm<<<dim3(16, 32), dim3(256), 0, stream>>>(aob, wT, out, 4096, 2048, 2048);
}

// Round 3
// 710.582 us; speedup vs baseline: 1.0913x; 1.0913x over previous
//
#include <hip/hip_runtime.h>

typedef unsigned short u16;
typedef __attribute__((ext_vector_type(8))) short short8;
typedef __attribute__((ext_vector_type(4))) unsigned short ushort4v;
typedef __attribute__((ext_vector_type(8))) unsigned short ushort8v;
typedef __attribute__((ext_vector_type(4))) float f32x4;

#define MFMA_16x16x32(a, b, c) __builtin_amdgcn_mfma_f32_16x16x32_bf16(a, b, c, 0, 0, 0)

// async global->LDS DMA, 16B per lane; LDS dest = wave-uniform base + lane*16
#define GLOAD16(g, l)                                                              \
    __builtin_amdgcn_global_load_lds(                                              \
        (const __attribute__((address_space(1))) unsigned int*)(g),                \
        (__attribute__((address_space(3))) unsigned int*)(l), 16, 0, 0)

__device__ __forceinline__ u16 f2bf(float f) {
    unsigned int u = __float_as_uint(f);
    u += 0x7fffu + ((u >> 16) & 1u);
    return (u16)(u >> 16);
}

// ---------------- elementwise cast fp32 -> bf16 (8 elems/thread) ----------------
__global__ __launch_bounds__(256) void k_cast(const float* __restrict__ in, u16* __restrict__ out) {
    long i = ((long)blockIdx.x * 256 + threadIdx.x) * 8;
    f32x4 a = *(const f32x4*)(in + i);
    f32x4 b = *(const f32x4*)(in + i + 4);
    ushort8v o;
    o[0] = f2bf(a[0]); o[1] = f2bf(a[1]); o[2] = f2bf(a[2]); o[3] = f2bf(a[3]);
    o[4] = f2bf(b[0]); o[5] = f2bf(b[1]); o[6] = f2bf(b[2]); o[7] = f2bf(b[3]);
    *(ushort8v*)(out + i) = o;
}

// ---------------- transpose + cast: in fp32 [R][C] (+z*ibs) -> out bf16 [C][R] (+z*obs) ----------------
__global__ __launch_bounds__(256) void k_tcast(const float* __restrict__ in, u16* __restrict__ out,
                                               int R, int C, long ibs, long obs) {
    __shared__ float tile[32][33];
    const int t = threadIdx.x;
    const int tx = t & 31, ty = t >> 5;
    const long r0 = (long)blockIdx.y * 32, c0 = (long)blockIdx.x * 32;
    const float* ip = in + (long)blockIdx.z * ibs;
    u16* op = out + (long)blockIdx.z * obs;
#pragma unroll
    for (int i = 0; i < 4; i++)
        tile[ty + 8 * i][tx] = ip[(r0 + ty + 8 * i) * C + c0 + tx];
    __syncthreads();
#pragma unroll
    for (int i = 0; i < 4; i++)
        op[(c0 + ty + 8 * i) * R + r0 + tx] = f2bf(tile[tx][ty + 8 * i]);
}

// ---------------- GEMM body: C[M][N] = A[M][K] * B, with Bt[N][K]; m97 structure ----------------
// 128x128 tile, BK=32, 4 waves (2x2 of 64x64), linear LDS [128][32], global_load_lds x16.
__device__ __forceinline__ void gemm_body(const u16* __restrict__ A, const u16* __restrict__ Bt,
                                          float* __restrict__ C, int N, int K) {
    __shared__ u16 As[128 * 32];
    __shared__ u16 Bs[128 * 32];
    const int t = threadIdx.x;
    const int lane = t & 63, wave = t >> 6;
    const long m0 = (long)blockIdx.y * 128, n0 = (long)blockIdx.x * 128;
    const int wm = (wave >> 1) * 64, wn = (wave & 1) * 64;
    const u16* Ag = A + (m0 + (t >> 2)) * (long)K + (t & 3) * 8;
    const u16* Bg = Bt + (n0 + (t >> 2)) * (long)K + (t & 3) * 8;
    u16* lA = As + wave * 512;  // wave-uniform LDS base; lane*16B appended by HW
    u16* lB = Bs + wave * 512;
    const int fr = lane & 15, fg = (lane >> 4) * 8;
    const f32x4 z = {0.f, 0.f, 0.f, 0.f};
    f32x4 acc[4][4];
#pragma unroll
    for (int i = 0; i < 4; i++)
#pragma unroll
        for (int j = 0; j < 4; j++) acc[i][j] = z;
    for (int k0 = 0; k0 < K; k0 += 32) {
        __syncthreads();
        GLOAD16(Ag + k0, lA);
        GLOAD16(Ag + (long)64 * K + k0, lA + 2048);
        GLOAD16(Bg + k0, lB);
        GLOAD16(Bg + (long)64 * K + k0, lB + 2048);
        __syncthreads();
        short8 af[4], bf[4];
#pragma unroll
        for (int i = 0; i < 4; i++) {
            af[i] = *(const short8*)&As[(wm + i * 16 + fr) * 32 + fg];
            bf[i] = *(const short8*)&Bs[(wn + i * 16 + fr) * 32 + fg];
        }
#pragma unroll
        for (int i = 0; i < 4; i++)
#pragma unroll
            for (int j = 0; j < 4; j++)
                acc[i][j] = MFMA_16x16x32(af[i], bf[j], acc[i][j]);
    }
    const int cr = (lane >> 4) * 4, cc = lane & 15;
#pragma unroll
    for (int i = 0; i < 4; i++)
#pragma unroll
        for (int j = 0; j < 4; j++)
#pragma unroll
            for (int r = 0; r < 4; r++)
                C[(m0 + wm + i * 16 + cr + r) * N + (n0 + wn + j * 16 + cc)] = acc[i][j][r];
}

__global__ __launch_bounds__(256) void k_gemm(const u16* __restrict__ A, const u16* __restrict__ Bt,
                                              float* __restrict__ C, int N, int K) {
    gemm_body(A, Bt, C, N, K);
}

// two independent small GEMMs batched via blockIdx.z (occupancy: 128 -> 256 blocks)
__global__ __launch_bounds__(256) void k_gemm2(const u16* __restrict__ A,
                                               const u16* __restrict__ Bt0, const u16* __restrict__ Bt1,
                                               float* __restrict__ C0, float* __restrict__ C1,
                                               int N, int K) {
    gemm_body(A, blockIdx.z ? Bt1 : Bt0, blockIdx.z ? C1 : C0, N, K);
}

// ---------------- LayerNorm over 2048 cols (+ optional RoPE) -> bf16 [B,H,Srows,128] ----------------
__global__ __launch_bounds__(256) void k_ln(const float* __restrict__ in, const float* __restrict__ w,
                                            const float* __restrict__ bia, const float* __restrict__ freqs,
                                            u16* __restrict__ out, int Srows, float eps, int do_rope) {
    const int row = blockIdx.x;
    const int bi = row / Srows, s = row - bi * Srows;
    const int t = threadIdx.x;
    const long base = (long)row * 2048 + t * 8;
    f32x4 v0 = *(const f32x4*)(in + base);
    f32x4 v1 = *(const f32x4*)(in + base + 4);
    float sum = 0.f, sq = 0.f;
#pragma unroll
    for (int r = 0; r < 4; r++) {
        sum += v0[r] + v1[r];
        sq += v0[r] * v0[r] + v1[r] * v1[r];
    }
#pragma unroll
    for (int off = 32; off >= 1; off >>= 1) {
        sum += __shfl_xor(sum, off);
        sq += __shfl_xor(sq, off);
    }
    __shared__ float red[8];
    const int wv = t >> 6, lane = t & 63;
    if (lane == 0) { red[wv] = sum; red[4 + wv] = sq; }
    __syncthreads();
    sum = red[0] + red[1] + red[2] + red[3];
    sq  = red[4] + red[5] + red[6] + red[7];
    const float mu = sum * (1.f / 2048.f);
    const float rstd = rsqrtf(sq * (1.f / 2048.f) - mu * mu + eps);
    const int c0 = t * 8;
    f32x4 w0 = *(const f32x4*)(w + c0), w1 = *(const f32x4*)(w + c0 + 4);
    f32x4 b0 = *(const f32x4*)(bia + c0), b1 = *(const f32x4*)(bia + c0 + 4);
    float nv[8];
#pragma unroll
    for (int r = 0; r < 4; r++) {
        nv[r]     = (v0[r] - mu) * rstd * w0[r] + b0[r];
        nv[4 + r] = (v1[r] - mu) * rstd * w1[r] + b1[r];
    }
    if (do_rope) {
        const float* fp = freqs + ((long)s * 64 + ((c0 & 127) >> 1)) * 2;
        f32x4 f0 = *(const f32x4*)(fp), f1 = *(const f32x4*)(fp + 4);
        float t0, t1;
        t0 = nv[0]; t1 = nv[1]; nv[0] = t0 * f0[0] - t1 * f0[1]; nv[1] = t0 * f0[1] + t1 * f0[0];
        t0 = nv[2]; t1 = nv[3]; nv[2] = t0 * f0[2] - t1 * f0[3]; nv[3] = t0 * f0[3] + t1 * f0[2];
        t0 = nv[4]; t1 = nv[5]; nv[4] = t0 * f1[0] - t1 * f1[1]; nv[5] = t0 * f1[1] + t1 * f1[0];
        t0 = nv[6]; t1 = nv[7]; nv[6] = t0 * f1[2] - t1 * f1[3]; nv[7] = t0 * f1[3] + t1 * f1[2];
    }
    const int h = c0 >> 7;
    ushort8v o;
#pragma unroll
    for (int r = 0; r < 8; r++) o[r] = f2bf(nv[r]);
    *(ushort8v*)(out + (((long)bi * 16 + h) * Srows + s) * 128 + (c0 & 127)) = o;
}

// ---------------- fused dual flash attention ----------------
// Q,K: [B,H,S,128] bf16; Vt: [B,H,128,S]; Yk: [B,H,512,128]; Yvt: [B,H,128,512]
// out: [B,S,H*128] bf16.  Block: 256 thr = 4 waves, each wave 16 q-rows; 32-key tiles.
__global__ __launch_bounds__(256) void k_attn(const u16* __restrict__ Q, const u16* __restrict__ Kg,
                                              const u16* __restrict__ Vt, const u16* __restrict__ Yk,
                                              const u16* __restrict__ Yvt, const float* __restrict__ gate,
                                              u16* __restrict__ Out) {
    __shared__ u16 Ks[32 * 136];
    __shared__ u16 Vs[128 * 40];
    __shared__ u16 Ps[4][16 * 40];
    const int t = threadIdx.x, lane = t & 63, wave = t >> 6;
    const int h = blockIdx.y, b = blockIdx.z;
    const int q0 = blockIdx.x * 64 + wave * 16;
    const long bh = (long)b * 16 + h;
    const int fr = lane & 15;
    const int g = lane >> 4;
    const int fg8 = g * 8;
    const float scale = 0.08838834764831845f;  // 1/sqrt(128)
    const f32x4 z = {0.f, 0.f, 0.f, 0.f};

    // Q fragments (B-operand: col = q-row = fr, k = d)
    const u16* qp = Q + (bh * 2048 + q0 + fr) * 128;
    short8 qf[4];
#pragma unroll
    for (int ks = 0; ks < 4; ks++) qf[ks] = *(const short8*)(qp + fg8 + ks * 32);

    f32x4 o1[8], o2[8];

    auto flash = [&](const u16* kp, const u16* vp, int L, int vstride, f32x4* oout) {
        float m = -3.0e38f, l = 0.f;
        f32x4 oacc[8];
#pragma unroll
        for (int i = 0; i < 8; i++) oacc[i] = z;
        for (int kb = 0; kb < L; kb += 32) {
            __syncthreads();
#pragma unroll
            for (int i = 0; i < 2; i++) {  // stage K tile 32x128
                int idx = t + 256 * i;
                int r = idx >> 4, c = (idx & 15) * 8;
                *(short8*)&Ks[r * 136 + c] = *(const short8*)(kp + (long)(kb + r) * 128 + c);
            }
#pragma unroll
            for (int i = 0; i < 2; i++) {  // stage Vt tile 128x32
                int idx = t + 256 * i;
                int r = idx >> 2, c = (idx & 3) * 8;
                *(short8*)&Vs[r * 40 + c] = *(const short8*)(vp + (long)r * vstride + kb + c);
            }
            __syncthreads();
            // S^T = K * Q^T : col=q (fr), row=key_local (4g+r)
            f32x4 c0 = z, c1 = z;
#pragma unroll
            for (int ks = 0; ks < 4; ks++) {
                short8 k0f = *(const short8*)&Ks[fr * 136 + fg8 + ks * 32];
                short8 k1f = *(const short8*)&Ks[(16 + fr) * 136 + fg8 + ks * 32];
                c0 = MFMA_16x16x32(k0f, qf[ks], c0);
                c1 = MFMA_16x16x32(k1f, qf[ks], c1);
            }
            float s[8];
#pragma unroll
            for (int r = 0; r < 4; r++) { s[r] = c0[r] * scale; s[4 + r] = c1[r] * scale; }
            float tmax = s[0];
#pragma unroll
            for (int r = 1; r < 8; r++) tmax = fmaxf(tmax, s[r]);
            tmax = fmaxf(tmax, __shfl_xor(tmax, 16));
            tmax = fmaxf(tmax, __shfl_xor(tmax, 32));
            if (!__all(tmax <= m + 8.f)) {  // defer-max rescale
                float mn = fmaxf(m, tmax);
                float corr = __expf(m - mn);
#pragma unroll
                for (int i = 0; i < 8; i++) oacc[i] *= corr;
                l *= corr;
                m = mn;
            }
            float p[8], ts = 0.f;
#pragma unroll
            for (int r = 0; r < 8; r++) { p[r] = __expf(s[r] - m); ts += p[r]; }
            ts += __shfl_xor(ts, 16);
            ts += __shfl_xor(ts, 32);
            l += ts;
            ushort4v pk0, pk1;
#pragma unroll
            for (int r = 0; r < 4; r++) { pk0[r] = f2bf(p[r]); pk1[r] = f2bf(p[4 + r]); }
            // P stored [q][key] so PV B-frag is a single contiguous b128 read
            *(ushort4v*)&Ps[wave][fr * 40 + g * 4] = pk0;
            *(ushort4v*)&Ps[wave][fr * 40 + 16 + g * 4] = pk1;
            short8 pf = *(const short8*)&Ps[wave][fr * 40 + fg8];
#pragma unroll
            for (int dt = 0; dt < 8; dt++) {  // O^T += V^T * P^T
                short8 vf = *(const short8*)&Vs[(dt * 16 + fr) * 40 + fg8];
                oacc[dt] = MFMA_16x16x32(vf, pf, oacc[dt]);
            }
        }
        float inv = 1.f / l;
#pragma unroll
        for (int i = 0; i < 8; i++) oout[i] = oacc[i] * inv;
    };

    flash(Kg + bh * 2048 * 128, Vt + bh * 128 * 2048, 2048, 2048, o1);
    flash(Yk + bh * 512 * 128, Yvt + bh * 128 * 512, 512, 512, o2);

    const float tg = tanhf(gate[h]);
    u16* op = Out + ((long)b * 2048 + q0 + fr) * 2048 + h * 128;
#pragma unroll
    for (int dt = 0; dt < 8; dt++) {
        ushort4v w4;
#pragma unroll
        for (int r = 0; r < 4; r++) w4[r] = f2bf(o1[dt][r] + tg * o2[dt][r]);
        *(ushort4v*)(op + dt * 16 + g * 4) = w4;
    }
}

extern "C" void kernel_launch(void* const* d_in, const int* in_sizes, int n_in,
                              void* d_out, int out_size, void* d_ws, size_t ws_size,
                              hipStream_t stream) {
    (void)in_sizes; (void)n_in; (void)out_size; (void)ws_size;
    const float* x     = (const float*)d_in[0];
    const float* freqs = (const float*)d_in[2];
    const float* y     = (const float*)d_in[3];
    const float* wq    = (const float*)d_in[5];
    const float* wk    = (const float*)d_in[6];
    const float* wv    = (const float*)d_in[7];
    const float* wo    = (const float*)d_in[8];
    const float* wky   = (const float*)d_in[9];
    const float* wvy   = (const float*)d_in[10];
    const float* gate  = (const float*)d_in[11];
    const float* qn_w  = (const float*)d_in[12];
    const float* qn_b  = (const float*)d_in[13];
    const float* kn_w  = (const float*)d_in[14];
    const float* kn_b  = (const float*)d_in[15];
    const float* kyn_w = (const float*)d_in[16];
    const float* kyn_b = (const float*)d_in[17];
    float* out = (float*)d_out;

    char* p = (char*)d_ws;
    u16* xb   = (u16*)p; p += 4096L * 2048 * 2;
    u16* yb   = (u16*)p; p += 1024L * 2048 * 2;
    u16* wT   = (u16*)p; p += 2048L * 2048 * 2;
    u16* qb   = (u16*)p; p += 4096L * 2048 * 2;
    u16* kbuf = (u16*)p; p += 4096L * 2048 * 2;
    u16* vtb  = (u16*)p; p += 4096L * 2048 * 2;
    u16* ykb  = (u16*)p; p += 1024L * 2048 * 2;
    u16* yvtb = (u16*)p; p += 1024L * 2048 * 2;
    u16* aob  = (u16*)p; p += 4096L * 2048 * 2;
    float* raw = out;  // d_out doubles as fp32 scratch (exactly 4096x2048 fp32)
    // scratch aliases for the batched small-GEMM pair (regions dead at that point):
    u16* wT2   = ykb;          // 8.4 MB spanning ykb+yvtb, consumed before ykb/yvtb written
    float* rawB = (float*)aob; // 8.4 MB inside aob (written by k_attn much later)

    k_cast<<<dim3(4096), dim3(256), 0, stream>>>(x, xb);
    k_cast<<<dim3(1024), dim3(256), 0, stream>>>(y, yb);

    // Q path
    k_tcast<<<dim3(64, 64, 1), dim3(256), 0, stream>>>(wq, wT, 2048, 2048, 0, 0);
    k_gemm<<<dim3(16, 32), dim3(256), 0, stream>>>(xb, wT, raw, 2048, 2048);
    k_ln<<<dim3(4096), dim3(256), 0, stream>>>(raw, qn_w, qn_b, freqs, qb, 2048, 1e-5f, 1);
    // K path
    k_tcast<<<dim3(64, 64, 1), dim3(256), 0, stream>>>(wk, wT, 2048, 2048, 0, 0);
    k_gemm<<<dim3(16, 32), dim3(256), 0, stream>>>(xb, wT, raw, 2048, 2048);
    k_ln<<<dim3(4096), dim3(256), 0, stream>>>(raw, kn_w, kn_b, freqs, kbuf, 2048, 1e-5f, 1);
    // V path (transpose to [B,H,128,S])
    k_tcast<<<dim3(64, 64, 1), dim3(256), 0, stream>>>(wv, wT, 2048, 2048, 0, 0);
    k_gemm<<<dim3(16, 32), dim3(256), 0, stream>>>(xb, wT, raw, 2048, 2048);
    k_tcast<<<dim3(64, 64, 2), dim3(256), 0, stream>>>(raw, vtb, 2048, 2048, 2048L * 2048, 2048L * 2048);
    // yK + yV paths, batched GEMM (z=2)
    k_tcast<<<dim3(64, 64, 1), dim3(256), 0, stream>>>(wky, wT, 2048, 2048, 0, 0);
    k_tcast<<<dim3(64, 64, 1), dim3(256), 0, stream>>>(wvy, wT2, 2048, 2048, 0, 0);
    k_gemm2<<<dim3(16, 8, 2), dim3(256), 0, stream>>>(yb, wT, wT2, raw, rawB, 2048, 2048);
    k_ln<<<dim3(1024), dim3(256), 0, stream>>>(raw, kyn_w, kyn_b, freqs, ykb, 512, 1e-6f, 0);
    k_tcast<<<dim3(64, 16, 2), dim3(256), 0, stream>>>(rawB, yvtb, 512, 2048, 512L * 2048, 2048L * 512);
    // fused dual attention
    k_attn<<<dim3(32, 16, 2), dim3(256), 0, stream>>>(qb, kbuf, vtb, ykb, yvtb, gate, aob);
    // output projection
    k_tcast<<<dim3(64, 64, 1), dim3(256), 0, stream>>>(wo, wT, 2048, 2048, 0, 0);
    k_gemm<<<dim3(16, 32), dim3(256), 0, stream>>>(aob, wT, out, 2048, 2048);
}

// Round 6
// 662.344 us; speedup vs baseline: 1.1707x; 1.0728x over previous
//
#include <hip/hip_runtime.h>

typedef unsigned short u16;
typedef __attribute__((ext_vector_type(8))) short short8;
typedef __attribute__((ext_vector_type(4))) unsigned short ushort4v;
typedef __attribute__((ext_vector_type(8))) unsigned short ushort8v;
typedef __attribute__((ext_vector_type(4))) float f32x4;

#define MFMA_16x16x32(a, b, c) __builtin_amdgcn_mfma_f32_16x16x32_bf16(a, b, c, 0, 0, 0)

// async global->LDS DMA, 16B per lane; LDS dest = wave-uniform base + lane*16
#define GLOAD16(g, l)                                                              \
    __builtin_amdgcn_global_load_lds(                                              \
        (const __attribute__((address_space(1))) unsigned int*)(g),                \
        (__attribute__((address_space(3))) unsigned int*)(l), 16, 0, 0)

__device__ __forceinline__ u16 f2bf(float f) {
    unsigned int u = __float_as_uint(f);
    u += 0x7fffu + ((u >> 16) & 1u);
    return (u16)(u >> 16);
}

// ---------------- elementwise cast fp32 -> bf16 (8 elems/thread) ----------------
__global__ __launch_bounds__(256) void k_cast(const float* __restrict__ in, u16* __restrict__ out) {
    long i = ((long)blockIdx.x * 256 + threadIdx.x) * 8;
    f32x4 a = *(const f32x4*)(in + i);
    f32x4 b = *(const f32x4*)(in + i + 4);
    ushort8v o;
    o[0] = f2bf(a[0]); o[1] = f2bf(a[1]); o[2] = f2bf(a[2]); o[3] = f2bf(a[3]);
    o[4] = f2bf(b[0]); o[5] = f2bf(b[1]); o[6] = f2bf(b[2]); o[7] = f2bf(b[3]);
    *(ushort8v*)(out + i) = o;
}

// ---------------- transpose + cast: in fp32 [R][C] (+z*ibs) -> out bf16 [C][R] (+z*obs) ----------------
__global__ __launch_bounds__(256) void k_tcast(const float* __restrict__ in, u16* __restrict__ out,
                                               int R, int C, long ibs, long obs) {
    __shared__ float tile[32][33];
    const int t = threadIdx.x;
    const int tx = t & 31, ty = t >> 5;
    const long r0 = (long)blockIdx.y * 32, c0 = (long)blockIdx.x * 32;
    const float* ip = in + (long)blockIdx.z * ibs;
    u16* op = out + (long)blockIdx.z * obs;
#pragma unroll
    for (int i = 0; i < 4; i++)
        tile[ty + 8 * i][tx] = ip[(r0 + ty + 8 * i) * C + c0 + tx];
    __syncthreads();
#pragma unroll
    for (int i = 0; i < 4; i++)
        op[(c0 + ty + 8 * i) * R + r0 + tx] = f2bf(tile[tx][ty + 8 * i]);
}

// ---------------- GEMM body: C[M][N] = A[M][K] * B, with Bt[N][K]; m97 structure ----------------
// 128x128 tile, BK=32, 4 waves (2x2 of 64x64), linear LDS [128][32], global_load_lds x16.
__device__ __forceinline__ void gemm_body(const u16* __restrict__ A, const u16* __restrict__ Bt,
                                          float* __restrict__ C, int N, int K) {
    __shared__ u16 As[128 * 32];
    __shared__ u16 Bs[128 * 32];
    const int t = threadIdx.x;
    const int lane = t & 63, wave = t >> 6;
    const long m0 = (long)blockIdx.y * 128, n0 = (long)blockIdx.x * 128;
    const int wm = (wave >> 1) * 64, wn = (wave & 1) * 64;
    const u16* Ag = A + (m0 + (t >> 2)) * (long)K + (t & 3) * 8;
    const u16* Bg = Bt + (n0 + (t >> 2)) * (long)K + (t & 3) * 8;
    u16* lA = As + wave * 512;  // wave-uniform LDS base; lane*16B appended by HW
    u16* lB = Bs + wave * 512;
    const int fr = lane & 15, fg = (lane >> 4) * 8;
    const f32x4 z = {0.f, 0.f, 0.f, 0.f};
    f32x4 acc[4][4];
#pragma unroll
    for (int i = 0; i < 4; i++)
#pragma unroll
        for (int j = 0; j < 4; j++) acc[i][j] = z;
    for (int k0 = 0; k0 < K; k0 += 32) {
        __syncthreads();
        GLOAD16(Ag + k0, lA);
        GLOAD16(Ag + (long)64 * K + k0, lA + 2048);
        GLOAD16(Bg + k0, lB);
        GLOAD16(Bg + (long)64 * K + k0, lB + 2048);
        __syncthreads();
        short8 af[4], bf[4];
#pragma unroll
        for (int i = 0; i < 4; i++) {
            af[i] = *(const short8*)&As[(wm + i * 16 + fr) * 32 + fg];
            bf[i] = *(const short8*)&Bs[(wn + i * 16 + fr) * 32 + fg];
        }
#pragma unroll
        for (int i = 0; i < 4; i++)
#pragma unroll
            for (int j = 0; j < 4; j++)
                acc[i][j] = MFMA_16x16x32(af[i], bf[j], acc[i][j]);
    }
    const int cr = (lane >> 4) * 4, cc = lane & 15;
#pragma unroll
    for (int i = 0; i < 4; i++)
#pragma unroll
        for (int j = 0; j < 4; j++)
#pragma unroll
            for (int r = 0; r < 4; r++)
                C[(m0 + wm + i * 16 + cr + r) * N + (n0 + wn + j * 16 + cc)] = acc[i][j][r];
}

__global__ __launch_bounds__(256) void k_gemm(const u16* __restrict__ A, const u16* __restrict__ Bt,
                                              float* __restrict__ C, int N, int K) {
    gemm_body(A, Bt, C, N, K);
}

// two independent small GEMMs batched via blockIdx.z (occupancy: 128 -> 256 blocks)
__global__ __launch_bounds__(256) void k_gemm2(const u16* __restrict__ A,
                                               const u16* __restrict__ Bt0, const u16* __restrict__ Bt1,
                                               float* __restrict__ C0, float* __restrict__ C1,
                                               int N, int K) {
    gemm_body(A, blockIdx.z ? Bt1 : Bt0, blockIdx.z ? C1 : C0, N, K);
}

// ---------------- LayerNorm over 2048 cols (+ optional RoPE) -> bf16 [B,H,Srows,128] ----------------
__global__ __launch_bounds__(256) void k_ln(const float* __restrict__ in, const float* __restrict__ w,
                                            const float* __restrict__ bia, const float* __restrict__ freqs,
                                            u16* __restrict__ out, int Srows, float eps, int do_rope) {
    const int row = blockIdx.x;
    const int bi = row / Srows, s = row - bi * Srows;
    const int t = threadIdx.x;
    const long base = (long)row * 2048 + t * 8;
    f32x4 v0 = *(const f32x4*)(in + base);
    f32x4 v1 = *(const f32x4*)(in + base + 4);
    float sum = 0.f, sq = 0.f;
#pragma unroll
    for (int r = 0; r < 4; r++) {
        sum += v0[r] + v1[r];
        sq += v0[r] * v0[r] + v1[r] * v1[r];
    }
#pragma unroll
    for (int off = 32; off >= 1; off >>= 1) {
        sum += __shfl_xor(sum, off);
        sq += __shfl_xor(sq, off);
    }
    __shared__ float red[8];
    const int wv = t >> 6, lane = t & 63;
    if (lane == 0) { red[wv] = sum; red[4 + wv] = sq; }
    __syncthreads();
    sum = red[0] + red[1] + red[2] + red[3];
    sq  = red[4] + red[5] + red[6] + red[7];
    const float mu = sum * (1.f / 2048.f);
    const float rstd = rsqrtf(sq * (1.f / 2048.f) - mu * mu + eps);
    const int c0 = t * 8;
    f32x4 w0 = *(const f32x4*)(w + c0), w1 = *(const f32x4*)(w + c0 + 4);
    f32x4 b0 = *(const f32x4*)(bia + c0), b1 = *(const f32x4*)(bia + c0 + 4);
    float nv[8];
#pragma unroll
    for (int r = 0; r < 4; r++) {
        nv[r]     = (v0[r] - mu) * rstd * w0[r] + b0[r];
        nv[4 + r] = (v1[r] - mu) * rstd * w1[r] + b1[r];
    }
    if (do_rope) {
        const float* fp = freqs + ((long)s * 64 + ((c0 & 127) >> 1)) * 2;
        f32x4 f0 = *(const f32x4*)(fp), f1 = *(const f32x4*)(fp + 4);
        float t0, t1;
        t0 = nv[0]; t1 = nv[1]; nv[0] = t0 * f0[0] - t1 * f0[1]; nv[1] = t0 * f0[1] + t1 * f0[0];
        t0 = nv[2]; t1 = nv[3]; nv[2] = t0 * f0[2] - t1 * f0[3]; nv[3] = t0 * f0[3] + t1 * f0[2];
        t0 = nv[4]; t1 = nv[5]; nv[4] = t0 * f1[0] - t1 * f1[1]; nv[5] = t0 * f1[1] + t1 * f1[0];
        t0 = nv[6]; t1 = nv[7]; nv[6] = t0 * f1[2] - t1 * f1[3]; nv[7] = t0 * f1[3] + t1 * f1[2];
    }
    const int h = c0 >> 7;
    ushort8v o;
#pragma unroll
    for (int r = 0; r < 8; r++) o[r] = f2bf(nv[r]);
    *(ushort8v*)(out + (((long)bi * 16 + h) * Srows + s) * 128 + (c0 & 127)) = o;
}

// ---------------- fused dual flash attention (v2: async gload_lds double-buffer) ----------------
// Q,K: [B,H,S,128] bf16; Vt: [B,H,128,S]; Yk: [B,H,512,128]; Yvt: [B,H,128,512]
// out: [B,S,H*128] bf16.  Block: 256 thr = 4 waves, each wave 16 q-rows; 32-key tiles.
// K LDS linear [32][128] with T21 XOR swizzle: source col ^= (row&7)*8, read col ^= (fr&7)*8.
// V LDS linear [128][32] (stride 64B: conflict-free). One barrier per tile.
__global__ __launch_bounds__(256, 4) void k_attn(const u16* __restrict__ Q, const u16* __restrict__ Kg,
                                                 const u16* __restrict__ Vt, const u16* __restrict__ Yk,
                                                 const u16* __restrict__ Yvt, const float* __restrict__ gate,
                                                 u16* __restrict__ Out) {
    __shared__ u16 Ks[2][32 * 128];
    __shared__ u16 Vs[2][128 * 32];
    __shared__ u16 Ps[4][16 * 40];
    const int t = threadIdx.x, lane = t & 63, wave = t >> 6;
    const int h = blockIdx.y, b = blockIdx.z;
    const int q0 = blockIdx.x * 64 + wave * 16;
    const long bh = (long)b * 16 + h;
    const int fr = lane & 15;
    const int g = lane >> 4;
    const int fg8 = g * 8;
    const float scale = 0.08838834764831845f;  // 1/sqrt(128)
    const f32x4 z = {0.f, 0.f, 0.f, 0.f};

    // staging geometry (per wave: 2 K-issues + 2 V-issues of 1KB each)
    const int kr0 = (wave * 2 + 0) * 4 + (lane >> 4);      // K rows for issue 0/1
    const int kr1 = (wave * 2 + 1) * 4 + (lane >> 4);
    const int kc0 = ((lane & 15) ^ (kr0 & 7)) * 8;          // inverse-swizzled source col
    const int kc1 = ((lane & 15) ^ (kr1 & 7)) * 8;
    const int vr0 = (wave * 2 + 0) * 16 + (lane >> 2);      // V rows for issue 0/1
    const int vr1 = (wave * 2 + 1) * 16 + (lane >> 2);
    const int vc = (lane & 3) * 8;

    // Q fragments (B-operand: col = q-row = fr, k = d)
    const u16* qp = Q + (bh * 2048 + q0 + fr) * 128;
    short8 qf[4];
#pragma unroll
    for (int ks = 0; ks < 4; ks++) qf[ks] = *(const short8*)(qp + fg8 + ks * 32);

    f32x4 o1[8], o2[8];
    const int sw = (fr & 7) * 8;  // read-side swizzle (same for rows fr and fr+16)

    auto stage = [&](int buf, const u16* kp, const u16* vp, int kb, long vstride) {
        GLOAD16(kp + (long)(kb + kr0) * 128 + kc0, &Ks[buf][(wave * 2 + 0) * 512]);
        GLOAD16(kp + (long)(kb + kr1) * 128 + kc1, &Ks[buf][(wave * 2 + 1) * 512]);
        GLOAD16(vp + (long)vr0 * vstride + kb + vc, &Vs[buf][(wave * 2 + 0) * 512]);
        GLOAD16(vp + (long)vr1 * vstride + kb + vc, &Vs[buf][(wave * 2 + 1) * 512]);
    };

    auto flash = [&](const u16* kp, const u16* vp, int L, long vstride, f32x4* oout) {
        float m = -3.0e38f, l = 0.f;
        f32x4 oacc[8];
#pragma unroll
        for (int i = 0; i < 8; i++) oacc[i] = z;
        stage(0, kp, vp, 0, vstride);
        __syncthreads();
        const int nt = L / 32;
        for (int ti = 0; ti < nt; ti++) {
            const int cur = ti & 1;
            if (ti + 1 < nt) stage(cur ^ 1, kp, vp, (ti + 1) * 32, vstride);
            // S^T = K * Q^T : col=q (fr), row=key_local (4g+r)
            f32x4 c0 = z, c1 = z;
#pragma unroll
            for (int ks = 0; ks < 4; ks++) {
                short8 k0f = *(const short8*)&Ks[cur][fr * 128 + ((fg8 + ks * 32) ^ sw)];
                short8 k1f = *(const short8*)&Ks[cur][(16 + fr) * 128 + ((fg8 + ks * 32) ^ sw)];
                c0 = MFMA_16x16x32(k0f, qf[ks], c0);
                c1 = MFMA_16x16x32(k1f, qf[ks], c1);
            }
            float s[8];
#pragma unroll
            for (int r = 0; r < 4; r++) { s[r] = c0[r] * scale; s[4 + r] = c1[r] * scale; }
            float tmax = s[0];
#pragma unroll
            for (int r = 1; r < 8; r++) tmax = fmaxf(tmax, s[r]);
            tmax = fmaxf(tmax, __shfl_xor(tmax, 16));
            tmax = fmaxf(tmax, __shfl_xor(tmax, 32));
            if (!__all(tmax <= m + 8.f)) {  // defer-max rescale
                float mn = fmaxf(m, tmax);
                float corr = __expf(m - mn);
#pragma unroll
                for (int i = 0; i < 8; i++) oacc[i] *= corr;
                l *= corr;
                m = mn;
            }
            float p[8], ts = 0.f;
#pragma unroll
            for (int r = 0; r < 8; r++) { p[r] = __expf(s[r] - m); ts += p[r]; }
            ts += __shfl_xor(ts, 16);
            ts += __shfl_xor(ts, 32);
            l += ts;
            ushort4v pk0, pk1;
#pragma unroll
            for (int r = 0; r < 4; r++) { pk0[r] = f2bf(p[r]); pk1[r] = f2bf(p[4 + r]); }
            // P stored [q][key] so PV B-frag is a single contiguous b128 read
            *(ushort4v*)&Ps[wave][fr * 40 + g * 4] = pk0;
            *(ushort4v*)&Ps[wave][fr * 40 + 16 + g * 4] = pk1;
            short8 pf = *(const short8*)&Ps[wave][fr * 40 + fg8];
#pragma unroll
            for (int dt = 0; dt < 8; dt++) {  // O^T += V^T * P^T
                short8 vf = *(const short8*)&Vs[cur][(dt * 16 + fr) * 32 + fg8];
                oacc[dt] = MFMA_16x16x32(vf, pf, oacc[dt]);
            }
            __syncthreads();  // implicit vmcnt(0)+lgkmcnt(0): next-tile DMA landed, all reads of cur done
        }
        float inv = 1.f / l;
#pragma unroll
        for (int i = 0; i < 8; i++) oout[i] = oacc[i] * inv;
    };

    flash(Kg + bh * 2048 * 128, Vt + bh * 128 * 2048, 2048, 2048, o1);
    flash(Yk + bh * 512 * 128, Yvt + bh * 128 * 512, 512, 512, o2);

    const float tg = tanhf(gate[h]);
    u16* op = Out + ((long)b * 2048 + q0 + fr) * 2048 + h * 128;
#pragma unroll
    for (int dt = 0; dt < 8; dt++) {
        ushort4v w4;
#pragma unroll
        for (int r = 0; r < 4; r++) w4[r] = f2bf(o1[dt][r] + tg * o2[dt][r]);
        *(ushort4v*)(op + dt * 16 + g * 4) = w4;
    }
}

extern "C" void kernel_launch(void* const* d_in, const int* in_sizes, int n_in,
                              void* d_out, int out_size, void* d_ws, size_t ws_size,
                              hipStream_t stream) {
    (void)in_sizes; (void)n_in; (void)out_size; (void)ws_size;
    const float* x     = (const float*)d_in[0];
    const float* freqs = (const float*)d_in[2];
    const float* y     = (const float*)d_in[3];
    const float* wq    = (const float*)d_in[5];
    const float* wk    = (const float*)d_in[6];
    const float* wv    = (const float*)d_in[7];
    const float* wo    = (const float*)d_in[8];
    const float* wky   = (const float*)d_in[9];
    const float* wvy   = (const float*)d_in[10];
    const float* gate  = (const float*)d_in[11];
    const float* qn_w  = (const float*)d_in[12];
    const float* qn_b  = (const float*)d_in[13];
    const float* kn_w  = (const float*)d_in[14];
    const float* kn_b  = (const float*)d_in[15];
    const float* kyn_w = (const float*)d_in[16];
    const float* kyn_b = (const float*)d_in[17];
    float* out = (float*)d_out;

    char* p = (char*)d_ws;
    u16* xb   = (u16*)p; p += 4096L * 2048 * 2;
    u16* yb   = (u16*)p; p += 1024L * 2048 * 2;
    u16* wT   = (u16*)p; p += 2048L * 2048 * 2;
    u16* qb   = (u16*)p; p += 4096L * 2048 * 2;
    u16* kbuf = (u16*)p; p += 4096L * 2048 * 2;
    u16* vtb  = (u16*)p; p += 4096L * 2048 * 2;
    u16* ykb  = (u16*)p; p += 1024L * 2048 * 2;
    u16* yvtb = (u16*)p; p += 1024L * 2048 * 2;
    u16* aob  = (u16*)p; p += 4096L * 2048 * 2;
    float* raw = out;  // d_out doubles as fp32 scratch (exactly 4096x2048 fp32)
    // scratch aliases for the batched small-GEMM pair (regions dead at that point):
    u16* wT2   = ykb;          // 8.4 MB spanning ykb+yvtb, consumed before ykb/yvtb written
    float* rawB = (float*)aob; // 8.4 MB inside aob (written by k_attn much later)

    k_cast<<<dim3(4096), dim3(256), 0, stream>>>(x, xb);
    k_cast<<<dim3(1024), dim3(256), 0, stream>>>(y, yb);

    // Q path
    k_tcast<<<dim3(64, 64, 1), dim3(256), 0, stream>>>(wq, wT, 2048, 2048, 0, 0);
    k_gemm<<<dim3(16, 32), dim3(256), 0, stream>>>(xb, wT, raw, 2048, 2048);
    k_ln<<<dim3(4096), dim3(256), 0, stream>>>(raw, qn_w, qn_b, freqs, qb, 2048, 1e-5f, 1);
    // K path
    k_tcast<<<dim3(64, 64, 1), dim3(256), 0, stream>>>(wk, wT, 2048, 2048, 0, 0);
    k_gemm<<<dim3(16, 32), dim3(256), 0, stream>>>(xb, wT, raw, 2048, 2048);
    k_ln<<<dim3(4096), dim3(256), 0, stream>>>(raw, kn_w, kn_b, freqs, kbuf, 2048, 1e-5f, 1);
    // V path (transpose to [B,H,128,S])
    k_tcast<<<dim3(64, 64, 1), dim3(256), 0, stream>>>(wv, wT, 2048, 2048, 0, 0);
    k_gemm<<<dim3(16, 32), dim3(256), 0, stream>>>(xb, wT, raw, 2048, 2048);
    k_tcast<<<dim3(64, 64, 2), dim3(256), 0, stream>>>(raw, vtb, 2048, 2048, 2048L * 2048, 2048L * 2048);
    // yK + yV paths, batched GEMM (z=2)
    k_tcast<<<dim3(64, 64, 1), dim3(256), 0, stream>>>(wky, wT, 2048, 2048, 0, 0);
    k_tcast<<<dim3(64, 64, 1), dim3(256), 0, stream>>>(wvy, wT2, 2048, 2048, 0, 0);
    k_gemm2<<<dim3(16, 8, 2), dim3(256), 0, stream>>>(yb, wT, wT2, raw, rawB, 2048, 2048);
    k_ln<<<dim3(1024), dim3(256), 0, stream>>>(raw, kyn_w, kyn_b, freqs, ykb, 512, 1e-6f, 0);
    k_tcast<<<dim3(64, 16, 2), dim3(256), 0, stream>>>(rawB, yvtb, 512, 2048, 512L * 2048, 2048L * 512);
    // fused dual attention
    k_attn<<<dim3(32, 16, 2), dim3(256), 0, stream>>>(qb, kbuf, vtb, ykb, yvtb, gate, aob);
    // output projection
    k_tcast<<<dim3(64, 64, 1), dim3(256), 0, stream>>>(wo, wT, 2048, 2048, 0, 0);
    k_gemm<<<dim3(16, 32), dim3(256), 0, stream>>>(aob, wT, out, 2048, 2048);
}

// Round 7
// 641.856 us; speedup vs baseline: 1.2081x; 1.0319x over previous
//
#include <hip/hip_runtime.h>

typedef unsigned short u16;
typedef __attribute__((ext_vector_type(8))) short short8;
typedef __attribute__((ext_vector_type(4))) unsigned short ushort4v;
typedef __attribute__((ext_vector_type(8))) unsigned short ushort8v;
typedef __attribute__((ext_vector_type(4))) float f32x4;

#define MFMA_16x16x32(a, b, c) __builtin_amdgcn_mfma_f32_16x16x32_bf16(a, b, c, 0, 0, 0)

// async global->LDS DMA, 16B per lane; LDS dest = wave-uniform base + lane*16
#define GLOAD16(g, l)                                                              \
    __builtin_amdgcn_global_load_lds(                                              \
        (const __attribute__((address_space(1))) unsigned int*)(g),                \
        (__attribute__((address_space(3))) unsigned int*)(l), 16, 0, 0)

__device__ __forceinline__ u16 f2bf(float f) {
    unsigned int u = __float_as_uint(f);
    u += 0x7fffu + ((u >> 16) & 1u);
    return (u16)(u >> 16);
}
__device__ __forceinline__ float bf2f(u16 v) {
    return __uint_as_float(((unsigned int)v) << 16);
}

// ---------------- elementwise cast fp32 -> bf16 (8 elems/thread) ----------------
__global__ __launch_bounds__(256) void k_cast(const float* __restrict__ in, u16* __restrict__ out) {
    long i = ((long)blockIdx.x * 256 + threadIdx.x) * 8;
    f32x4 a = *(const f32x4*)(in + i);
    f32x4 b = *(const f32x4*)(in + i + 4);
    ushort8v o;
    o[0] = f2bf(a[0]); o[1] = f2bf(a[1]); o[2] = f2bf(a[2]); o[3] = f2bf(a[3]);
    o[4] = f2bf(b[0]); o[5] = f2bf(b[1]); o[6] = f2bf(b[2]); o[7] = f2bf(b[3]);
    *(ushort8v*)(out + i) = o;
}

// ---------------- transpose + cast: in fp32 [R][C] (+z*ibs) -> out bf16 [C][R] (+z*obs) ----------------
__global__ __launch_bounds__(256) void k_tcast(const float* __restrict__ in, u16* __restrict__ out,
                                               int R, int C, long ibs, long obs) {
    __shared__ float tile[32][33];
    const int t = threadIdx.x;
    const int tx = t & 31, ty = t >> 5;
    const long r0 = (long)blockIdx.y * 32, c0 = (long)blockIdx.x * 32;
    const float* ip = in + (long)blockIdx.z * ibs;
    u16* op = out + (long)blockIdx.z * obs;
#pragma unroll
    for (int i = 0; i < 4; i++)
        tile[ty + 8 * i][tx] = ip[(r0 + ty + 8 * i) * C + c0 + tx];
    __syncthreads();
#pragma unroll
    for (int i = 0; i < 4; i++)
        op[(c0 + ty + 8 * i) * R + r0 + tx] = f2bf(tile[tx][ty + 8 * i]);
}

// ---------------- transpose bf16 -> bf16: in [R][C] (+z*ibs) -> out [C][R] (+z*obs) ----------------
__global__ __launch_bounds__(256) void k_tcast_bf(const u16* __restrict__ in, u16* __restrict__ out,
                                                  int R, int C, long ibs, long obs) {
    __shared__ u16 tile[32][34];
    const int t = threadIdx.x;
    const int tx = t & 31, ty = t >> 5;
    const long r0 = (long)blockIdx.y * 32, c0 = (long)blockIdx.x * 32;
    const u16* ip = in + (long)blockIdx.z * ibs;
    u16* op = out + (long)blockIdx.z * obs;
#pragma unroll
    for (int i = 0; i < 4; i++)
        tile[ty + 8 * i][tx] = ip[(r0 + ty + 8 * i) * C + c0 + tx];
    __syncthreads();
#pragma unroll
    for (int i = 0; i < 4; i++)
        op[(c0 + ty + 8 * i) * R + r0 + tx] = tile[tx][ty + 8 * i];
}

// ---------------- GEMM body: C[M][N] = A[M][K] * B, with Bt[N][K]; m97 structure ----------------
// 128x128 tile, BK=32, 4 waves (2x2 of 64x64), linear LDS [128][32], global_load_lds x16.
__device__ __forceinline__ void gemm_body(const u16* __restrict__ A, const u16* __restrict__ Bt,
                                          float* __restrict__ C, int N, int K) {
    __shared__ u16 As[128 * 32];
    __shared__ u16 Bs[128 * 32];
    const int t = threadIdx.x;
    const int lane = t & 63, wave = t >> 6;
    const long m0 = (long)blockIdx.y * 128, n0 = (long)blockIdx.x * 128;
    const int wm = (wave >> 1) * 64, wn = (wave & 1) * 64;
    const u16* Ag = A + (m0 + (t >> 2)) * (long)K + (t & 3) * 8;
    const u16* Bg = Bt + (n0 + (t >> 2)) * (long)K + (t & 3) * 8;
    u16* lA = As + wave * 512;  // wave-uniform LDS base; lane*16B appended by HW
    u16* lB = Bs + wave * 512;
    const int fr = lane & 15, fg = (lane >> 4) * 8;
    const f32x4 z = {0.f, 0.f, 0.f, 0.f};
    f32x4 acc[4][4];
#pragma unroll
    for (int i = 0; i < 4; i++)
#pragma unroll
        for (int j = 0; j < 4; j++) acc[i][j] = z;
    for (int k0 = 0; k0 < K; k0 += 32) {
        __syncthreads();
        GLOAD16(Ag + k0, lA);
        GLOAD16(Ag + (long)64 * K + k0, lA + 2048);
        GLOAD16(Bg + k0, lB);
        GLOAD16(Bg + (long)64 * K + k0, lB + 2048);
        __syncthreads();
        short8 af[4], bf[4];
#pragma unroll
        for (int i = 0; i < 4; i++) {
            af[i] = *(const short8*)&As[(wm + i * 16 + fr) * 32 + fg];
            bf[i] = *(const short8*)&Bs[(wn + i * 16 + fr) * 32 + fg];
        }
#pragma unroll
        for (int i = 0; i < 4; i++)
#pragma unroll
            for (int j = 0; j < 4; j++)
                acc[i][j] = MFMA_16x16x32(af[i], bf[j], acc[i][j]);
    }
    const int cr = (lane >> 4) * 4, cc = lane & 15;
#pragma unroll
    for (int i = 0; i < 4; i++)
#pragma unroll
        for (int j = 0; j < 4; j++)
#pragma unroll
            for (int r = 0; r < 4; r++)
                C[(m0 + wm + i * 16 + cr + r) * N + (n0 + wn + j * 16 + cc)] = acc[i][j][r];
}

__global__ __launch_bounds__(256) void k_gemm(const u16* __restrict__ A, const u16* __restrict__ Bt,
                                              float* __restrict__ C, int N, int K) {
    gemm_body(A, Bt, C, N, K);
}

// two independent small GEMMs batched via blockIdx.z
__global__ __launch_bounds__(256) void k_gemm2(const u16* __restrict__ A,
                                               const u16* __restrict__ Bt0, const u16* __restrict__ Bt1,
                                               float* __restrict__ C0, float* __restrict__ C1,
                                               int N, int K) {
    gemm_body(A, blockIdx.z ? Bt1 : Bt0, blockIdx.z ? C1 : C0, N, K);
}

// ---------------- merged QKV GEMM: N=6144 (3 segments of 2048), per-segment B + output routing ----
// seg0 (Q): fp32 out.  seg1 (K), seg2 (V): bf16 out.
__global__ __launch_bounds__(256) void k_gemm3(const u16* __restrict__ A,
                                               const u16* __restrict__ Bq, const u16* __restrict__ Bk,
                                               const u16* __restrict__ Bv,
                                               float* __restrict__ Cq, u16* __restrict__ Ck,
                                               u16* __restrict__ Cv, int K) {
    __shared__ u16 As[128 * 32];
    __shared__ u16 Bs[128 * 32];
    const int t = threadIdx.x;
    const int lane = t & 63, wave = t >> 6;
    const long m0 = (long)blockIdx.y * 128;
    const int n0 = blockIdx.x * 128;
    const int seg = n0 >> 11;            // 0=Q 1=K 2=V
    const int ncol = n0 & 2047;
    const u16* Bt = (seg == 0) ? Bq : ((seg == 1) ? Bk : Bv);
    const int wm = (wave >> 1) * 64, wn = (wave & 1) * 64;
    const u16* Ag = A + (m0 + (t >> 2)) * (long)K + (t & 3) * 8;
    const u16* Bg = Bt + (ncol + (t >> 2)) * (long)K + (t & 3) * 8;
    u16* lA = As + wave * 512;
    u16* lB = Bs + wave * 512;
    const int fr = lane & 15, fg = (lane >> 4) * 8;
    const f32x4 z = {0.f, 0.f, 0.f, 0.f};
    f32x4 acc[4][4];
#pragma unroll
    for (int i = 0; i < 4; i++)
#pragma unroll
        for (int j = 0; j < 4; j++) acc[i][j] = z;
    for (int k0 = 0; k0 < K; k0 += 32) {
        __syncthreads();
        GLOAD16(Ag + k0, lA);
        GLOAD16(Ag + (long)64 * K + k0, lA + 2048);
        GLOAD16(Bg + k0, lB);
        GLOAD16(Bg + (long)64 * K + k0, lB + 2048);
        __syncthreads();
        short8 af[4], bf[4];
#pragma unroll
        for (int i = 0; i < 4; i++) {
            af[i] = *(const short8*)&As[(wm + i * 16 + fr) * 32 + fg];
            bf[i] = *(const short8*)&Bs[(wn + i * 16 + fr) * 32 + fg];
        }
#pragma unroll
        for (int i = 0; i < 4; i++)
#pragma unroll
            for (int j = 0; j < 4; j++)
                acc[i][j] = MFMA_16x16x32(af[i], bf[j], acc[i][j]);
    }
    const int cr = (lane >> 4) * 4, cc = lane & 15;
    if (seg == 0) {
#pragma unroll
        for (int i = 0; i < 4; i++)
#pragma unroll
            for (int j = 0; j < 4; j++)
#pragma unroll
                for (int r = 0; r < 4; r++)
                    Cq[(m0 + wm + i * 16 + cr + r) * 2048 + (ncol + wn + j * 16 + cc)] = acc[i][j][r];
    } else {
        u16* Co = (seg == 1) ? Ck : Cv;
#pragma unroll
        for (int i = 0; i < 4; i++)
#pragma unroll
            for (int j = 0; j < 4; j++)
#pragma unroll
                for (int r = 0; r < 4; r++)
                    Co[(m0 + wm + i * 16 + cr + r) * 2048 + (ncol + wn + j * 16 + cc)] = f2bf(acc[i][j][r]);
    }
}

// ---------------- LayerNorm over 2048 cols (+ optional RoPE) -> bf16 [B,H,Srows,128] ----------------
__device__ __forceinline__ void ln_core(float nv[8], const float* __restrict__ w,
                                        const float* __restrict__ bia, const float* __restrict__ freqs,
                                        u16* __restrict__ out, int bi, int s, int Srows,
                                        float eps, int do_rope, int t) {
    float sum = 0.f, sq = 0.f;
#pragma unroll
    for (int r = 0; r < 8; r++) { sum += nv[r]; sq += nv[r] * nv[r]; }
#pragma unroll
    for (int off = 32; off >= 1; off >>= 1) {
        sum += __shfl_xor(sum, off);
        sq += __shfl_xor(sq, off);
    }
    __shared__ float red[8];
    const int wv = t >> 6, lane = t & 63;
    if (lane == 0) { red[wv] = sum; red[4 + wv] = sq; }
    __syncthreads();
    sum = red[0] + red[1] + red[2] + red[3];
    sq  = red[4] + red[5] + red[6] + red[7];
    const float mu = sum * (1.f / 2048.f);
    const float rstd = rsqrtf(sq * (1.f / 2048.f) - mu * mu + eps);
    const int c0 = t * 8;
    f32x4 w0 = *(const f32x4*)(w + c0), w1 = *(const f32x4*)(w + c0 + 4);
    f32x4 b0 = *(const f32x4*)(bia + c0), b1 = *(const f32x4*)(bia + c0 + 4);
#pragma unroll
    for (int r = 0; r < 4; r++) {
        nv[r]     = (nv[r] - mu) * rstd * w0[r] + b0[r];
        nv[4 + r] = (nv[4 + r] - mu) * rstd * w1[r] + b1[r];
    }
    if (do_rope) {
        const float* fp = freqs + ((long)s * 64 + ((c0 & 127) >> 1)) * 2;
        f32x4 f0 = *(const f32x4*)(fp), f1 = *(const f32x4*)(fp + 4);
        float t0, t1;
        t0 = nv[0]; t1 = nv[1]; nv[0] = t0 * f0[0] - t1 * f0[1]; nv[1] = t0 * f0[1] + t1 * f0[0];
        t0 = nv[2]; t1 = nv[3]; nv[2] = t0 * f0[2] - t1 * f0[3]; nv[3] = t0 * f0[3] + t1 * f0[2];
        t0 = nv[4]; t1 = nv[5]; nv[4] = t0 * f1[0] - t1 * f1[1]; nv[5] = t0 * f1[1] + t1 * f1[0];
        t0 = nv[6]; t1 = nv[7]; nv[6] = t0 * f1[2] - t1 * f1[3]; nv[7] = t0 * f1[3] + t1 * f1[2];
    }
    const int h = c0 >> 7;
    ushort8v o;
#pragma unroll
    for (int r = 0; r < 8; r++) o[r] = f2bf(nv[r]);
    *(ushort8v*)(out + (((long)bi * 16 + h) * Srows + s) * 128 + (c0 & 127)) = o;
}

__global__ __launch_bounds__(256) void k_ln(const float* __restrict__ in, const float* __restrict__ w,
                                            const float* __restrict__ bia, const float* __restrict__ freqs,
                                            u16* __restrict__ out, int Srows, float eps, int do_rope) {
    const int row = blockIdx.x;
    const int bi = row / Srows, s = row - bi * Srows;
    const int t = threadIdx.x;
    const long base = (long)row * 2048 + t * 8;
    f32x4 v0 = *(const f32x4*)(in + base);
    f32x4 v1 = *(const f32x4*)(in + base + 4);
    float nv[8] = {v0[0], v0[1], v0[2], v0[3], v1[0], v1[1], v1[2], v1[3]};
    ln_core(nv, w, bia, freqs, out, bi, s, Srows, eps, do_rope, t);
}

__global__ __launch_bounds__(256) void k_ln_bf(const u16* __restrict__ in, const float* __restrict__ w,
                                               const float* __restrict__ bia, const float* __restrict__ freqs,
                                               u16* __restrict__ out, int Srows, float eps, int do_rope) {
    const int row = blockIdx.x;
    const int bi = row / Srows, s = row - bi * Srows;
    const int t = threadIdx.x;
    ushort8v v = *(const ushort8v*)(in + (long)row * 2048 + t * 8);
    float nv[8];
#pragma unroll
    for (int r = 0; r < 8; r++) nv[r] = bf2f(v[r]);
    ln_core(nv, w, bia, freqs, out, bi, s, Srows, eps, do_rope, t);
}

// ---------------- fused dual flash attention (async gload_lds double-buffer, exp2 softmax) --------
__global__ __launch_bounds__(256, 4) void k_attn(const u16* __restrict__ Q, const u16* __restrict__ Kg,
                                                 const u16* __restrict__ Vt, const u16* __restrict__ Yk,
                                                 const u16* __restrict__ Yvt, const float* __restrict__ gate,
                                                 u16* __restrict__ Out) {
    __shared__ u16 Ks[2][32 * 128];
    __shared__ u16 Vs[2][128 * 32];
    __shared__ u16 Ps[4][16 * 40];
    const int t = threadIdx.x, lane = t & 63, wave = t >> 6;
    const int h = blockIdx.y, b = blockIdx.z;
    const int q0 = blockIdx.x * 64 + wave * 16;
    const long bh = (long)b * 16 + h;
    const int fr = lane & 15;
    const int g = lane >> 4;
    const int fg8 = g * 8;
    // log2-domain scale: 1/sqrt(128) * log2(e)
    const float scale2 = 0.08838834764831845f * 1.4426950408889634f;
    const f32x4 z = {0.f, 0.f, 0.f, 0.f};

    const int kr0 = (wave * 2 + 0) * 4 + (lane >> 4);
    const int kr1 = (wave * 2 + 1) * 4 + (lane >> 4);
    const int kc0 = ((lane & 15) ^ (kr0 & 7)) * 8;
    const int kc1 = ((lane & 15) ^ (kr1 & 7)) * 8;
    const int vr0 = (wave * 2 + 0) * 16 + (lane >> 2);
    const int vr1 = (wave * 2 + 1) * 16 + (lane >> 2);
    const int vc = (lane & 3) * 8;

    const u16* qp = Q + (bh * 2048 + q0 + fr) * 128;
    short8 qf[4];
#pragma unroll
    for (int ks = 0; ks < 4; ks++) qf[ks] = *(const short8*)(qp + fg8 + ks * 32);

    f32x4 o1[8], o2[8];
    const int sw = (fr & 7) * 8;

    auto stage = [&](int buf, const u16* kp, const u16* vp, int kb, long vstride) {
        GLOAD16(kp + (long)(kb + kr0) * 128 + kc0, &Ks[buf][(wave * 2 + 0) * 512]);
        GLOAD16(kp + (long)(kb + kr1) * 128 + kc1, &Ks[buf][(wave * 2 + 1) * 512]);
        GLOAD16(vp + (long)vr0 * vstride + kb + vc, &Vs[buf][(wave * 2 + 0) * 512]);
        GLOAD16(vp + (long)vr1 * vstride + kb + vc, &Vs[buf][(wave * 2 + 1) * 512]);
    };

    auto flash = [&](const u16* kp, const u16* vp, int L, long vstride, f32x4* oout) {
        float m = -3.0e38f, l = 0.f;
        f32x4 oacc[8];
#pragma unroll
        for (int i = 0; i < 8; i++) oacc[i] = z;
        stage(0, kp, vp, 0, vstride);
        __syncthreads();
        const int nt = L / 32;
        for (int ti = 0; ti < nt; ti++) {
            const int cur = ti & 1;
            if (ti + 1 < nt) stage(cur ^ 1, kp, vp, (ti + 1) * 32, vstride);
            f32x4 c0 = z, c1 = z;
#pragma unroll
            for (int ks = 0; ks < 4; ks++) {
                short8 k0f = *(const short8*)&Ks[cur][fr * 128 + ((fg8 + ks * 32) ^ sw)];
                short8 k1f = *(const short8*)&Ks[cur][(16 + fr) * 128 + ((fg8 + ks * 32) ^ sw)];
                c0 = MFMA_16x16x32(k0f, qf[ks], c0);
                c1 = MFMA_16x16x32(k1f, qf[ks], c1);
            }
            float s[8];
#pragma unroll
            for (int r = 0; r < 4; r++) { s[r] = c0[r] * scale2; s[4 + r] = c1[r] * scale2; }
            float t0 = fmaxf(fmaxf(s[0], s[1]), fmaxf(s[2], s[3]));
            float t1 = fmaxf(fmaxf(s[4], s[5]), fmaxf(s[6], s[7]));
            float tmax = fmaxf(t0, t1);
            tmax = fmaxf(tmax, __shfl_xor(tmax, 16));
            tmax = fmaxf(tmax, __shfl_xor(tmax, 32));
            if (!__all(tmax <= m + 8.f)) {  // defer-max rescale (log2 domain)
                float mn = fmaxf(m, tmax);
                float corr = exp2f(m - mn);
#pragma unroll
                for (int i = 0; i < 8; i++) oacc[i] *= corr;
                l *= corr;
                m = mn;
            }
            float p[8], ts = 0.f;
#pragma unroll
            for (int r = 0; r < 8; r++) { p[r] = exp2f(s[r] - m); ts += p[r]; }
            ts += __shfl_xor(ts, 16);
            ts += __shfl_xor(ts, 32);
            l += ts;
            ushort4v pk0, pk1;
#pragma unroll
            for (int r = 0; r < 4; r++) { pk0[r] = f2bf(p[r]); pk1[r] = f2bf(p[4 + r]); }
            *(ushort4v*)&Ps[wave][fr * 40 + g * 4] = pk0;
            *(ushort4v*)&Ps[wave][fr * 40 + 16 + g * 4] = pk1;
            short8 pf = *(const short8*)&Ps[wave][fr * 40 + fg8];
#pragma unroll
            for (int dt = 0; dt < 8; dt++) {
                short8 vf = *(const short8*)&Vs[cur][(dt * 16 + fr) * 32 + fg8];
                oacc[dt] = MFMA_16x16x32(vf, pf, oacc[dt]);
            }
            __syncthreads();
        }
        float inv = 1.f / l;
#pragma unroll
        for (int i = 0; i < 8; i++) oout[i] = oacc[i] * inv;
    };

    flash(Kg + bh * 2048 * 128, Vt + bh * 128 * 2048, 2048, 2048, o1);
    flash(Yk + bh * 512 * 128, Yvt + bh * 128 * 512, 512, 512, o2);

    const float tg = tanhf(gate[h]);
    u16* op = Out + ((long)b * 2048 + q0 + fr) * 2048 + h * 128;
#pragma unroll
    for (int dt = 0; dt < 8; dt++) {
        ushort4v w4;
#pragma unroll
        for (int r = 0; r < 4; r++) w4[r] = f2bf(o1[dt][r] + tg * o2[dt][r]);
        *(ushort4v*)(op + dt * 16 + g * 4) = w4;
    }
}

extern "C" void kernel_launch(void* const* d_in, const int* in_sizes, int n_in,
                              void* d_out, int out_size, void* d_ws, size_t ws_size,
                              hipStream_t stream) {
    (void)in_sizes; (void)n_in; (void)out_size; (void)ws_size;
    const float* x     = (const float*)d_in[0];
    const float* freqs = (const float*)d_in[2];
    const float* y     = (const float*)d_in[3];
    const float* wq    = (const float*)d_in[5];
    const float* wk    = (const float*)d_in[6];
    const float* wv    = (const float*)d_in[7];
    const float* wo    = (const float*)d_in[8];
    const float* wky   = (const float*)d_in[9];
    const float* wvy   = (const float*)d_in[10];
    const float* gate  = (const float*)d_in[11];
    const float* qn_w  = (const float*)d_in[12];
    const float* qn_b  = (const float*)d_in[13];
    const float* kn_w  = (const float*)d_in[14];
    const float* kn_b  = (const float*)d_in[15];
    const float* kyn_w = (const float*)d_in[16];
    const float* kyn_b = (const float*)d_in[17];
    float* out = (float*)d_out;

    char* p = (char*)d_ws;
    u16* xb   = (u16*)p; p += 4096L * 2048 * 2;
    u16* yb   = (u16*)p; p += 1024L * 2048 * 2;
    u16* wT   = (u16*)p; p += 2048L * 2048 * 2;  // wq^T / later wky^T / later wo^T
    u16* qb   = (u16*)p; p += 4096L * 2048 * 2;  // Q heads; earlier: wk^T
    u16* kbuf = (u16*)p; p += 4096L * 2048 * 2;  // K heads; earlier: wv^T
    u16* vtb  = (u16*)p; p += 4096L * 2048 * 2;  // V^T heads; earlier: K-raw bf16
    u16* ykb  = (u16*)p; p += 1024L * 2048 * 2;  // yK heads; +yvtb = wvy^T slot
    u16* yvtb = (u16*)p; p += 1024L * 2048 * 2;  // yV^T heads
    u16* aob  = (u16*)p; p += 4096L * 2048 * 2;  // attn out; earlier: V-raw bf16, yV-raw fp32
    float* raw = out;            // d_out doubles as fp32 scratch (4096x2048 fp32)
    u16* wTk   = qb;             // wk^T parking (qb dead until k_ln Q)
    u16* wTv   = kbuf;           // wv^T parking (kbuf dead until k_ln_bf K)
    u16* krawb = vtb;            // K GEMM bf16 out (vtb dead until tcast_bf)
    u16* vrawb = aob;            // V GEMM bf16 out (aob dead until attn)
    u16* wT2   = ykb;            // wvy^T parking (spans ykb+yvtb, dead until their writes)
    float* rawB = (float*)aob;   // yV GEMM fp32 out (aob dead again after tcast_bf)

    k_cast<<<dim3(4096), dim3(256), 0, stream>>>(x, xb);
    k_cast<<<dim3(1024), dim3(256), 0, stream>>>(y, yb);

    // merged QKV projection
    k_tcast<<<dim3(64, 64, 1), dim3(256), 0, stream>>>(wq, wT, 2048, 2048, 0, 0);
    k_tcast<<<dim3(64, 64, 1), dim3(256), 0, stream>>>(wk, wTk, 2048, 2048, 0, 0);
    k_tcast<<<dim3(64, 64, 1), dim3(256), 0, stream>>>(wv, wTv, 2048, 2048, 0, 0);
    k_gemm3<<<dim3(48, 32), dim3(256), 0, stream>>>(xb, wT, wTk, wTv, raw, krawb, vrawb, 2048);
    k_ln<<<dim3(4096), dim3(256), 0, stream>>>(raw, qn_w, qn_b, freqs, qb, 2048, 1e-5f, 1);
    k_ln_bf<<<dim3(4096), dim3(256), 0, stream>>>(krawb, kn_w, kn_b, freqs, kbuf, 2048, 1e-5f, 1);
    k_tcast_bf<<<dim3(64, 64, 2), dim3(256), 0, stream>>>(vrawb, vtb, 2048, 2048, 2048L * 2048, 2048L * 2048);

    // yK + yV paths, batched GEMM (z=2)
    k_tcast<<<dim3(64, 64, 1), dim3(256), 0, stream>>>(wky, wT, 2048, 2048, 0, 0);
    k_tcast<<<dim3(64, 64, 1), dim3(256), 0, stream>>>(wvy, wT2, 2048, 2048, 0, 0);
    k_gemm2<<<dim3(16, 8, 2), dim3(256), 0, stream>>>(yb, wT, wT2, raw, rawB, 2048, 2048);
    k_ln<<<dim3(1024), dim3(256), 0, stream>>>(raw, kyn_w, kyn_b, freqs, ykb, 512, 1e-6f, 0);
    k_tcast<<<dim3(64, 16, 2), dim3(256), 0, stream>>>(rawB, yvtb, 512, 2048, 512L * 2048, 2048L * 512);

    // fused dual attention
    k_attn<<<dim3(32, 16, 2), dim3(256), 0, stream>>>(qb, kbuf, vtb, ykb, yvtb, gate, aob);

    // output projection
    k_tcast<<<dim3(64, 64, 1), dim3(256), 0, stream>>>(wo, wT, 2048, 2048, 0, 0);
    k_gemm<<<dim3(16, 32), dim3(256), 0, stream>>>(aob, wT, out, 2048, 2048);
}

// Round 8
// 616.166 us; speedup vs baseline: 1.2585x; 1.0417x over previous
//
#include <hip/hip_runtime.h>

typedef unsigned short u16;
typedef __attribute__((ext_vector_type(8))) short short8;
typedef __attribute__((ext_vector_type(4))) unsigned short ushort4v;
typedef __attribute__((ext_vector_type(8))) unsigned short ushort8v;
typedef __attribute__((ext_vector_type(4))) float f32x4;
typedef __attribute__((ext_vector_type(2))) unsigned int uint2v;

#define MFMA_16x16x32(a, b, c) __builtin_amdgcn_mfma_f32_16x16x32_bf16(a, b, c, 0, 0, 0)

// async global->LDS DMA, 16B per lane; LDS dest = wave-uniform base + lane*16
#define GLOAD16(g, l)                                                              \
    __builtin_amdgcn_global_load_lds(                                              \
        (const __attribute__((address_space(1))) unsigned int*)(g),                \
        (__attribute__((address_space(3))) unsigned int*)(l), 16, 0, 0)

__device__ __forceinline__ u16 f2bf(float f) {
    unsigned int u = __float_as_uint(f);
    u += 0x7fffu + ((u >> 16) & 1u);
    return (u16)(u >> 16);
}
__device__ __forceinline__ float bf2f(u16 v) {
    return __uint_as_float(((unsigned int)v) << 16);
}
// 2 f32 -> packed 2x bf16 (RNE), single instruction
__device__ __forceinline__ unsigned int cvtpk_bf16(float a, float b) {
    unsigned int r;
    asm("v_cvt_pk_bf16_f32 %0, %1, %2" : "=v"(r) : "v"(a), "v"(b));
    return r;
}

// ---------------- merged cast fp32 -> bf16 for x (nblkA blocks) and y ----------------
__global__ __launch_bounds__(256) void k_cast2(const float* __restrict__ a, u16* __restrict__ oa,
                                               const float* __restrict__ b, u16* __restrict__ ob,
                                               int nblkA) {
    const int bid = blockIdx.x;
    const float* in = (bid < nblkA) ? a : b;
    u16* out = (bid < nblkA) ? oa : ob;
    const long base = (long)((bid < nblkA) ? bid : bid - nblkA) * 2048;
    long i = base + threadIdx.x * 8;
    f32x4 va = *(const f32x4*)(in + i);
    f32x4 vb = *(const f32x4*)(in + i + 4);
    ushort8v o;
    o[0] = f2bf(va[0]); o[1] = f2bf(va[1]); o[2] = f2bf(va[2]); o[3] = f2bf(va[3]);
    o[4] = f2bf(vb[0]); o[5] = f2bf(vb[1]); o[6] = f2bf(vb[2]); o[7] = f2bf(vb[3]);
    *(ushort8v*)(out + i) = o;
}

// ---------------- batched 2048x2048 transpose+cast fp32->bf16, z routes src/dst ----------------
__global__ __launch_bounds__(256) void k_tcastB(const float* __restrict__ s0, const float* __restrict__ s1,
                                                const float* __restrict__ s2, u16* __restrict__ d0,
                                                u16* __restrict__ d1, u16* __restrict__ d2) {
    __shared__ float tile[32][33];
    const int t = threadIdx.x;
    const int tx = t & 31, ty = t >> 5;
    const long r0 = (long)blockIdx.y * 32, c0 = (long)blockIdx.x * 32;
    const float* ip = blockIdx.z == 0 ? s0 : (blockIdx.z == 1 ? s1 : s2);
    u16* op = blockIdx.z == 0 ? d0 : (blockIdx.z == 1 ? d1 : d2);
#pragma unroll
    for (int i = 0; i < 4; i++)
        tile[ty + 8 * i][tx] = ip[(r0 + ty + 8 * i) * 2048 + c0 + tx];
    __syncthreads();
#pragma unroll
    for (int i = 0; i < 4; i++)
        op[(c0 + ty + 8 * i) * 2048 + r0 + tx] = f2bf(tile[tx][ty + 8 * i]);
}

// ---------------- generic transpose + cast: in fp32 [R][C] (+z*ibs) -> out bf16 [C][R] (+z*obs) ----
__global__ __launch_bounds__(256) void k_tcast(const float* __restrict__ in, u16* __restrict__ out,
                                               int R, int C, long ibs, long obs) {
    __shared__ float tile[32][33];
    const int t = threadIdx.x;
    const int tx = t & 31, ty = t >> 5;
    const long r0 = (long)blockIdx.y * 32, c0 = (long)blockIdx.x * 32;
    const float* ip = in + (long)blockIdx.z * ibs;
    u16* op = out + (long)blockIdx.z * obs;
#pragma unroll
    for (int i = 0; i < 4; i++)
        tile[ty + 8 * i][tx] = ip[(r0 + ty + 8 * i) * C + c0 + tx];
    __syncthreads();
#pragma unroll
    for (int i = 0; i < 4; i++)
        op[(c0 + ty + 8 * i) * R + r0 + tx] = f2bf(tile[tx][ty + 8 * i]);
}

// ---------------- transpose bf16 -> bf16: in [R][C] (+z*ibs) -> out [C][R] (+z*obs) ----------------
__global__ __launch_bounds__(256) void k_tcast_bf(const u16* __restrict__ in, u16* __restrict__ out,
                                                  int R, int C, long ibs, long obs) {
    __shared__ u16 tile[32][34];
    const int t = threadIdx.x;
    const int tx = t & 31, ty = t >> 5;
    const long r0 = (long)blockIdx.y * 32, c0 = (long)blockIdx.x * 32;
    const u16* ip = in + (long)blockIdx.z * ibs;
    u16* op = out + (long)blockIdx.z * obs;
#pragma unroll
    for (int i = 0; i < 4; i++)
        tile[ty + 8 * i][tx] = ip[(r0 + ty + 8 * i) * C + c0 + tx];
    __syncthreads();
#pragma unroll
    for (int i = 0; i < 4; i++)
        op[(c0 + ty + 8 * i) * R + r0 + tx] = tile[tx][ty + 8 * i];
}

// ---------------- GEMM body: C[M][N] = A[M][K] * B, with Bt[N][K]; m97 structure ----------------
__device__ __forceinline__ void gemm_body(const u16* __restrict__ A, const u16* __restrict__ Bt,
                                          float* __restrict__ C, int N, int K) {
    __shared__ u16 As[128 * 32];
    __shared__ u16 Bs[128 * 32];
    const int t = threadIdx.x;
    const int lane = t & 63, wave = t >> 6;
    const long m0 = (long)blockIdx.y * 128, n0 = (long)blockIdx.x * 128;
    const int wm = (wave >> 1) * 64, wn = (wave & 1) * 64;
    const u16* Ag = A + (m0 + (t >> 2)) * (long)K + (t & 3) * 8;
    const u16* Bg = Bt + (n0 + (t >> 2)) * (long)K + (t & 3) * 8;
    u16* lA = As + wave * 512;
    u16* lB = Bs + wave * 512;
    const int fr = lane & 15, fg = (lane >> 4) * 8;
    const f32x4 z = {0.f, 0.f, 0.f, 0.f};
    f32x4 acc[4][4];
#pragma unroll
    for (int i = 0; i < 4; i++)
#pragma unroll
        for (int j = 0; j < 4; j++) acc[i][j] = z;
    for (int k0 = 0; k0 < K; k0 += 32) {
        __syncthreads();
        GLOAD16(Ag + k0, lA);
        GLOAD16(Ag + (long)64 * K + k0, lA + 2048);
        GLOAD16(Bg + k0, lB);
        GLOAD16(Bg + (long)64 * K + k0, lB + 2048);
        __syncthreads();
        short8 af[4], bf[4];
#pragma unroll
        for (int i = 0; i < 4; i++) {
            af[i] = *(const short8*)&As[(wm + i * 16 + fr) * 32 + fg];
            bf[i] = *(const short8*)&Bs[(wn + i * 16 + fr) * 32 + fg];
        }
#pragma unroll
        for (int i = 0; i < 4; i++)
#pragma unroll
            for (int j = 0; j < 4; j++)
                acc[i][j] = MFMA_16x16x32(af[i], bf[j], acc[i][j]);
    }
    const int cr = (lane >> 4) * 4, cc = lane & 15;
#pragma unroll
    for (int i = 0; i < 4; i++)
#pragma unroll
        for (int j = 0; j < 4; j++)
#pragma unroll
            for (int r = 0; r < 4; r++)
                C[(m0 + wm + i * 16 + cr + r) * N + (n0 + wn + j * 16 + cc)] = acc[i][j][r];
}

__global__ __launch_bounds__(256) void k_gemm(const u16* __restrict__ A, const u16* __restrict__ Bt,
                                              float* __restrict__ C, int N, int K) {
    gemm_body(A, Bt, C, N, K);
}

__global__ __launch_bounds__(256) void k_gemm2(const u16* __restrict__ A,
                                               const u16* __restrict__ Bt0, const u16* __restrict__ Bt1,
                                               float* __restrict__ C0, float* __restrict__ C1,
                                               int N, int K) {
    gemm_body(A, blockIdx.z ? Bt1 : Bt0, blockIdx.z ? C1 : C0, N, K);
}

// ---------------- merged QKV GEMM: N=6144 (3 segments of 2048) ----------------
__global__ __launch_bounds__(256) void k_gemm3(const u16* __restrict__ A,
                                               const u16* __restrict__ Bq, const u16* __restrict__ Bk,
                                               const u16* __restrict__ Bv,
                                               float* __restrict__ Cq, u16* __restrict__ Ck,
                                               u16* __restrict__ Cv, int K) {
    __shared__ u16 As[128 * 32];
    __shared__ u16 Bs[128 * 32];
    const int t = threadIdx.x;
    const int lane = t & 63, wave = t >> 6;
    const long m0 = (long)blockIdx.y * 128;
    const int n0 = blockIdx.x * 128;
    const int seg = n0 >> 11;
    const int ncol = n0 & 2047;
    const u16* Bt = (seg == 0) ? Bq : ((seg == 1) ? Bk : Bv);
    const int wm = (wave >> 1) * 64, wn = (wave & 1) * 64;
    const u16* Ag = A + (m0 + (t >> 2)) * (long)K + (t & 3) * 8;
    const u16* Bg = Bt + (ncol + (t >> 2)) * (long)K + (t & 3) * 8;
    u16* lA = As + wave * 512;
    u16* lB = Bs + wave * 512;
    const int fr = lane & 15, fg = (lane >> 4) * 8;
    const f32x4 z = {0.f, 0.f, 0.f, 0.f};
    f32x4 acc[4][4];
#pragma unroll
    for (int i = 0; i < 4; i++)
#pragma unroll
        for (int j = 0; j < 4; j++) acc[i][j] = z;
    for (int k0 = 0; k0 < K; k0 += 32) {
        __syncthreads();
        GLOAD16(Ag + k0, lA);
        GLOAD16(Ag + (long)64 * K + k0, lA + 2048);
        GLOAD16(Bg + k0, lB);
        GLOAD16(Bg + (long)64 * K + k0, lB + 2048);
        __syncthreads();
        short8 af[4], bf[4];
#pragma unroll
        for (int i = 0; i < 4; i++) {
            af[i] = *(const short8*)&As[(wm + i * 16 + fr) * 32 + fg];
            bf[i] = *(const short8*)&Bs[(wn + i * 16 + fr) * 32 + fg];
        }
#pragma unroll
        for (int i = 0; i < 4; i++)
#pragma unroll
            for (int j = 0; j < 4; j++)
                acc[i][j] = MFMA_16x16x32(af[i], bf[j], acc[i][j]);
    }
    const int cr = (lane >> 4) * 4, cc = lane & 15;
    if (seg == 0) {
#pragma unroll
        for (int i = 0; i < 4; i++)
#pragma unroll
            for (int j = 0; j < 4; j++)
#pragma unroll
                for (int r = 0; r < 4; r++)
                    Cq[(m0 + wm + i * 16 + cr + r) * 2048 + (ncol + wn + j * 16 + cc)] = acc[i][j][r];
    } else {
        u16* Co = (seg == 1) ? Ck : Cv;
#pragma unroll
        for (int i = 0; i < 4; i++)
#pragma unroll
            for (int j = 0; j < 4; j++)
#pragma unroll
                for (int r = 0; r < 4; r++)
                    Co[(m0 + wm + i * 16 + cr + r) * 2048 + (ncol + wn + j * 16 + cc)] = f2bf(acc[i][j][r]);
    }
}

// ---------------- LayerNorm over 2048 cols (+ optional RoPE) -> bf16 [B,H,Srows,128] ----------------
__device__ __forceinline__ void ln_core(float nv[8], const float* __restrict__ w,
                                        const float* __restrict__ bia, const float* __restrict__ freqs,
                                        u16* __restrict__ out, int bi, int s, int Srows,
                                        float eps, int do_rope, int t) {
    float sum = 0.f, sq = 0.f;
#pragma unroll
    for (int r = 0; r < 8; r++) { sum += nv[r]; sq += nv[r] * nv[r]; }
#pragma unroll
    for (int off = 32; off >= 1; off >>= 1) {
        sum += __shfl_xor(sum, off);
        sq += __shfl_xor(sq, off);
    }
    __shared__ float red[8];
    const int wv = t >> 6, lane = t & 63;
    if (lane == 0) { red[wv] = sum; red[4 + wv] = sq; }
    __syncthreads();
    sum = red[0] + red[1] + red[2] + red[3];
    sq  = red[4] + red[5] + red[6] + red[7];
    const float mu = sum * (1.f / 2048.f);
    const float rstd = rsqrtf(sq * (1.f / 2048.f) - mu * mu + eps);
    const int c0 = t * 8;
    f32x4 w0 = *(const f32x4*)(w + c0), w1 = *(const f32x4*)(w + c0 + 4);
    f32x4 b0 = *(const f32x4*)(bia + c0), b1 = *(const f32x4*)(bia + c0 + 4);
#pragma unroll
    for (int r = 0; r < 4; r++) {
        nv[r]     = (nv[r] - mu) * rstd * w0[r] + b0[r];
        nv[4 + r] = (nv[4 + r] - mu) * rstd * w1[r] + b1[r];
    }
    if (do_rope) {
        const float* fp = freqs + ((long)s * 64 + ((c0 & 127) >> 1)) * 2;
        f32x4 f0 = *(const f32x4*)(fp), f1 = *(const f32x4*)(fp + 4);
        float t0, t1;
        t0 = nv[0]; t1 = nv[1]; nv[0] = t0 * f0[0] - t1 * f0[1]; nv[1] = t0 * f0[1] + t1 * f0[0];
        t0 = nv[2]; t1 = nv[3]; nv[2] = t0 * f0[2] - t1 * f0[3]; nv[3] = t0 * f0[3] + t1 * f0[2];
        t0 = nv[4]; t1 = nv[5]; nv[4] = t0 * f1[0] - t1 * f1[1]; nv[5] = t0 * f1[1] + t1 * f1[0];
        t0 = nv[6]; t1 = nv[7]; nv[6] = t0 * f1[2] - t1 * f1[3]; nv[7] = t0 * f1[3] + t1 * f1[2];
    }
    const int h = c0 >> 7;
    ushort8v o;
#pragma unroll
    for (int r = 0; r < 8; r++) o[r] = f2bf(nv[r]);
    *(ushort8v*)(out + (((long)bi * 16 + h) * Srows + s) * 128 + (c0 & 127)) = o;
}

__global__ __launch_bounds__(256) void k_ln(const float* __restrict__ in, const float* __restrict__ w,
                                            const float* __restrict__ bia, const float* __restrict__ freqs,
                                            u16* __restrict__ out, int Srows, float eps, int do_rope) {
    const int row = blockIdx.x;
    const int bi = row / Srows, s = row - bi * Srows;
    const int t = threadIdx.x;
    const long base = (long)row * 2048 + t * 8;
    f32x4 v0 = *(const f32x4*)(in + base);
    f32x4 v1 = *(const f32x4*)(in + base + 4);
    float nv[8] = {v0[0], v0[1], v0[2], v0[3], v1[0], v1[1], v1[2], v1[3]};
    ln_core(nv, w, bia, freqs, out, bi, s, Srows, eps, do_rope, t);
}

__global__ __launch_bounds__(256) void k_ln_bf(const u16* __restrict__ in, const float* __restrict__ w,
                                               const float* __restrict__ bia, const float* __restrict__ freqs,
                                               u16* __restrict__ out, int Srows, float eps, int do_rope) {
    const int row = blockIdx.x;
    const int bi = row / Srows, s = row - bi * Srows;
    const int t = threadIdx.x;
    ushort8v v = *(const ushort8v*)(in + (long)row * 2048 + t * 8);
    float nv[8];
#pragma unroll
    for (int r = 0; r < 8; r++) nv[r] = bf2f(v[r]);
    ln_core(nv, w, bia, freqs, out, bi, s, Srows, eps, do_rope, t);
}

// ---------------- fused dual flash attention (async dbuf, native-exp2 softmax, cvt_pk) ----------
__global__ __launch_bounds__(256, 4) void k_attn(const u16* __restrict__ Q, const u16* __restrict__ Kg,
                                                 const u16* __restrict__ Vt, const u16* __restrict__ Yk,
                                                 const u16* __restrict__ Yvt, const float* __restrict__ gate,
                                                 u16* __restrict__ Out) {
    __shared__ u16 Ks[2][32 * 128];
    __shared__ u16 Vs[2][128 * 32];
    __shared__ u16 Ps[4][16 * 40];
    const int t = threadIdx.x, lane = t & 63, wave = t >> 6;
    const int h = blockIdx.y, b = blockIdx.z;
    const int q0 = blockIdx.x * 64 + wave * 16;
    const long bh = (long)b * 16 + h;
    const int fr = lane & 15;
    const int g = lane >> 4;
    const int fg8 = g * 8;
    // log2-domain scale: 1/sqrt(128) * log2(e)
    const float scale2 = 0.08838834764831845f * 1.4426950408889634f;
    const f32x4 z = {0.f, 0.f, 0.f, 0.f};

    const int kr0 = (wave * 2 + 0) * 4 + (lane >> 4);
    const int kr1 = (wave * 2 + 1) * 4 + (lane >> 4);
    const int kc0 = ((lane & 15) ^ (kr0 & 7)) * 8;
    const int kc1 = ((lane & 15) ^ (kr1 & 7)) * 8;
    const int vr0 = (wave * 2 + 0) * 16 + (lane >> 2);
    const int vr1 = (wave * 2 + 1) * 16 + (lane >> 2);
    const int vc = (lane & 3) * 8;

    const u16* qp = Q + (bh * 2048 + q0 + fr) * 128;
    short8 qf[4];
#pragma unroll
    for (int ks = 0; ks < 4; ks++) qf[ks] = *(const short8*)(qp + fg8 + ks * 32);

    f32x4 o1[8], o2[8];
    const int sw = (fr & 7) * 8;

    auto stage = [&](int buf, const u16* kp, const u16* vp, int kb, long vstride) {
        GLOAD16(kp + (long)(kb + kr0) * 128 + kc0, &Ks[buf][(wave * 2 + 0) * 512]);
        GLOAD16(kp + (long)(kb + kr1) * 128 + kc1, &Ks[buf][(wave * 2 + 1) * 512]);
        GLOAD16(vp + (long)vr0 * vstride + kb + vc, &Vs[buf][(wave * 2 + 0) * 512]);
        GLOAD16(vp + (long)vr1 * vstride + kb + vc, &Vs[buf][(wave * 2 + 1) * 512]);
    };

    auto flash = [&](const u16* kp, const u16* vp, int L, long vstride, f32x4* oout) {
        float m = -3.0e38f, l = 0.f;
        f32x4 oacc[8];
#pragma unroll
        for (int i = 0; i < 8; i++) oacc[i] = z;
        stage(0, kp, vp, 0, vstride);
        __syncthreads();
        const int nt = L / 32;
        for (int ti = 0; ti < nt; ti++) {
            const int cur = ti & 1;
            if (ti + 1 < nt) stage(cur ^ 1, kp, vp, (ti + 1) * 32, vstride);
            f32x4 c0 = z, c1 = z;
#pragma unroll
            for (int ks = 0; ks < 4; ks++) {
                short8 k0f = *(const short8*)&Ks[cur][fr * 128 + ((fg8 + ks * 32) ^ sw)];
                short8 k1f = *(const short8*)&Ks[cur][(16 + fr) * 128 + ((fg8 + ks * 32) ^ sw)];
                c0 = MFMA_16x16x32(k0f, qf[ks], c0);
                c1 = MFMA_16x16x32(k1f, qf[ks], c1);
            }
            // raw-domain max (scale2 > 0 preserves order), one mul to scaled domain
            float r0 = fmaxf(fmaxf(c0[0], c0[1]), fmaxf(c0[2], c0[3]));
            float r1 = fmaxf(fmaxf(c1[0], c1[1]), fmaxf(c1[2], c1[3]));
            float rmax = fmaxf(r0, r1);
            rmax = fmaxf(rmax, __shfl_xor(rmax, 16));
            rmax = fmaxf(rmax, __shfl_xor(rmax, 32));
            const float tmax = rmax * scale2;
            if (!__all(tmax <= m + 8.f)) {  // defer-max rescale (log2 domain)
                float mn = fmaxf(m, tmax);
                float corr = __builtin_amdgcn_exp2f(m - mn);
#pragma unroll
                for (int i = 0; i < 8; i++) oacc[i] *= corr;
                l *= corr;
                m = mn;
            }
            float p[8], ts = 0.f;
#pragma unroll
            for (int r = 0; r < 4; r++) {
                p[r]     = __builtin_amdgcn_exp2f(__builtin_fmaf(c0[r], scale2, -m));
                p[4 + r] = __builtin_amdgcn_exp2f(__builtin_fmaf(c1[r], scale2, -m));
            }
#pragma unroll
            for (int r = 0; r < 8; r++) ts += p[r];
            ts += __shfl_xor(ts, 16);
            ts += __shfl_xor(ts, 32);
            l += ts;
            uint2v w0, w1;
            w0[0] = cvtpk_bf16(p[0], p[1]); w0[1] = cvtpk_bf16(p[2], p[3]);
            w1[0] = cvtpk_bf16(p[4], p[5]); w1[1] = cvtpk_bf16(p[6], p[7]);
            *(uint2v*)&Ps[wave][fr * 40 + g * 4] = w0;
            *(uint2v*)&Ps[wave][fr * 40 + 16 + g * 4] = w1;
            short8 pf = *(const short8*)&Ps[wave][fr * 40 + fg8];
#pragma unroll
            for (int dt = 0; dt < 8; dt++) {
                short8 vf = *(const short8*)&Vs[cur][(dt * 16 + fr) * 32 + fg8];
                oacc[dt] = MFMA_16x16x32(vf, pf, oacc[dt]);
            }
            __syncthreads();
        }
        float inv = 1.f / l;
#pragma unroll
        for (int i = 0; i < 8; i++) oout[i] = oacc[i] * inv;
    };

    flash(Kg + bh * 2048 * 128, Vt + bh * 128 * 2048, 2048, 2048, o1);
    flash(Yk + bh * 512 * 128, Yvt + bh * 128 * 512, 512, 512, o2);

    const float tg = tanhf(gate[h]);
    u16* op = Out + ((long)b * 2048 + q0 + fr) * 2048 + h * 128;
#pragma unroll
    for (int dt = 0; dt < 8; dt++) {
        ushort4v w4;
#pragma unroll
        for (int r = 0; r < 4; r++) w4[r] = f2bf(o1[dt][r] + tg * o2[dt][r]);
        *(ushort4v*)(op + dt * 16 + g * 4) = w4;
    }
}

extern "C" void kernel_launch(void* const* d_in, const int* in_sizes, int n_in,
                              void* d_out, int out_size, void* d_ws, size_t ws_size,
                              hipStream_t stream) {
    (void)in_sizes; (void)n_in; (void)out_size; (void)ws_size;
    const float* x     = (const float*)d_in[0];
    const float* freqs = (const float*)d_in[2];
    const float* y     = (const float*)d_in[3];
    const float* wq    = (const float*)d_in[5];
    const float* wk    = (const float*)d_in[6];
    const float* wv    = (const float*)d_in[7];
    const float* wo    = (const float*)d_in[8];
    const float* wky   = (const float*)d_in[9];
    const float* wvy   = (const float*)d_in[10];
    const float* gate  = (const float*)d_in[11];
    const float* qn_w  = (const float*)d_in[12];
    const float* qn_b  = (const float*)d_in[13];
    const float* kn_w  = (const float*)d_in[14];
    const float* kn_b  = (const float*)d_in[15];
    const float* kyn_w = (const float*)d_in[16];
    const float* kyn_b = (const float*)d_in[17];
    float* out = (float*)d_out;

    char* p = (char*)d_ws;
    u16* xb   = (u16*)p; p += 4096L * 2048 * 2;
    u16* yb   = (u16*)p; p += 1024L * 2048 * 2;
    u16* wT   = (u16*)p; p += 2048L * 2048 * 2;  // wq^T / later wky^T / later wo^T
    u16* qb   = (u16*)p; p += 4096L * 2048 * 2;  // Q heads; earlier: wk^T
    u16* kbuf = (u16*)p; p += 4096L * 2048 * 2;  // K heads; earlier: wv^T
    u16* vtb  = (u16*)p; p += 4096L * 2048 * 2;  // V^T heads; earlier: K-raw bf16
    u16* ykb  = (u16*)p; p += 1024L * 2048 * 2;  // yK heads; +yvtb = wvy^T slot
    u16* yvtb = (u16*)p; p += 1024L * 2048 * 2;  // yV^T heads
    u16* aob  = (u16*)p; p += 4096L * 2048 * 2;  // attn out; earlier: V-raw bf16, yV-raw fp32
    float* raw = out;            // d_out doubles as fp32 scratch (4096x2048 fp32)
    u16* wTk   = qb;             // wk^T parking (qb dead until k_ln Q)
    u16* wTv   = kbuf;           // wv^T parking (kbuf dead until k_ln_bf K)
    u16* krawb = vtb;            // K GEMM bf16 out (vtb dead until tcast_bf)
    u16* vrawb = aob;            // V GEMM bf16 out (aob dead until attn)
    u16* wT2   = ykb;            // wvy^T parking (spans ykb+yvtb, dead until their writes)
    float* rawB = (float*)aob;   // yV GEMM fp32 out (aob dead again after tcast_bf)

    // input casts (merged)
    k_cast2<<<dim3(5120), dim3(256), 0, stream>>>(x, xb, y, yb, 4096);

    // merged QKV projection (3 weight transposes batched)
    k_tcastB<<<dim3(64, 64, 3), dim3(256), 0, stream>>>(wq, wk, wv, wT, wTk, wTv);
    k_gemm3<<<dim3(48, 32), dim3(256), 0, stream>>>(xb, wT, wTk, wTv, raw, krawb, vrawb, 2048);
    k_ln<<<dim3(4096), dim3(256), 0, stream>>>(raw, qn_w, qn_b, freqs, qb, 2048, 1e-5f, 1);
    k_ln_bf<<<dim3(4096), dim3(256), 0, stream>>>(krawb, kn_w, kn_b, freqs, kbuf, 2048, 1e-5f, 1);
    k_tcast_bf<<<dim3(64, 64, 2), dim3(256), 0, stream>>>(vrawb, vtb, 2048, 2048, 2048L * 2048, 2048L * 2048);

    // yK + yV paths (2 weight transposes batched), batched GEMM (z=2)
    k_tcastB<<<dim3(64, 64, 2), dim3(256), 0, stream>>>(wky, wvy, wvy, wT, wT2, wT2);
    k_gemm2<<<dim3(16, 8, 2), dim3(256), 0, stream>>>(yb, wT, wT2, raw, rawB, 2048, 2048);
    k_ln<<<dim3(1024), dim3(256), 0, stream>>>(raw, kyn_w, kyn_b, freqs, ykb, 512, 1e-6f, 0);
    k_tcast<<<dim3(64, 16, 2), dim3(256), 0, stream>>>(rawB, yvtb, 512, 2048, 512L * 2048, 2048L * 512);

    // fused dual attention
    k_attn<<<dim3(32, 16, 2), dim3(256), 0, stream>>>(qb, kbuf, vtb, ykb, yvtb, gate, aob);

    // output projection
    k_tcastB<<<dim3(64, 64, 1), dim3(256), 0, stream>>>(wo, wo, wo, wT, wT, wT);
    k_gemm<<<dim3(16, 32), dim3(256), 0, stream>>>(aob, wT, out, 2048, 2048);
}

// Round 9
// 610.581 us; speedup vs baseline: 1.2700x; 1.0091x over previous
//
#include <hip/hip_runtime.h>

typedef unsigned short u16;
typedef __attribute__((ext_vector_type(8))) short short8;
typedef __attribute__((ext_vector_type(4))) unsigned short ushort4v;
typedef __attribute__((ext_vector_type(8))) unsigned short ushort8v;
typedef __attribute__((ext_vector_type(4))) float f32x4;
typedef __attribute__((ext_vector_type(2))) unsigned int uint2v;

#define MFMA_16x16x32(a, b, c) __builtin_amdgcn_mfma_f32_16x16x32_bf16(a, b, c, 0, 0, 0)

// async global->LDS DMA, 16B per lane; LDS dest = wave-uniform base + lane*16
#define GLOAD16(g, l)                                                              \
    __builtin_amdgcn_global_load_lds(                                              \
        (const __attribute__((address_space(1))) unsigned int*)(g),                \
        (__attribute__((address_space(3))) unsigned int*)(l), 16, 0, 0)

__device__ __forceinline__ u16 f2bf(float f) {
    unsigned int u = __float_as_uint(f);
    u += 0x7fffu + ((u >> 16) & 1u);
    return (u16)(u >> 16);
}
__device__ __forceinline__ float bf2f(u16 v) {
    return __uint_as_float(((unsigned int)v) << 16);
}
__device__ __forceinline__ unsigned int cvtpk_bf16(float a, float b) {
    unsigned int r;
    asm("v_cvt_pk_bf16_f32 %0, %1, %2" : "=v"(r) : "v"(a), "v"(b));
    return r;
}

// ---------------- merged cast fp32 -> bf16 for x (nblkA blocks) and y ----------------
__global__ __launch_bounds__(256) void k_cast2(const float* __restrict__ a, u16* __restrict__ oa,
                                               const float* __restrict__ b, u16* __restrict__ ob,
                                               int nblkA) {
    const int bid = blockIdx.x;
    const float* in = (bid < nblkA) ? a : b;
    u16* out = (bid < nblkA) ? oa : ob;
    const long base = (long)((bid < nblkA) ? bid : bid - nblkA) * 2048;
    long i = base + threadIdx.x * 8;
    f32x4 va = *(const f32x4*)(in + i);
    f32x4 vb = *(const f32x4*)(in + i + 4);
    ushort8v o;
    o[0] = f2bf(va[0]); o[1] = f2bf(va[1]); o[2] = f2bf(va[2]); o[3] = f2bf(va[3]);
    o[4] = f2bf(vb[0]); o[5] = f2bf(vb[1]); o[6] = f2bf(vb[2]); o[7] = f2bf(vb[3]);
    *(ushort8v*)(out + i) = o;
}

// ---------------- batched 2048x2048 transpose+cast fp32->bf16, z routes src/dst ----------------
__global__ __launch_bounds__(256) void k_tcastB(const float* __restrict__ s0, const float* __restrict__ s1,
                                                const float* __restrict__ s2, u16* __restrict__ d0,
                                                u16* __restrict__ d1, u16* __restrict__ d2) {
    __shared__ float tile[32][33];
    const int t = threadIdx.x;
    const int tx = t & 31, ty = t >> 5;
    const long r0 = (long)blockIdx.y * 32, c0 = (long)blockIdx.x * 32;
    const float* ip = blockIdx.z == 0 ? s0 : (blockIdx.z == 1 ? s1 : s2);
    u16* op = blockIdx.z == 0 ? d0 : (blockIdx.z == 1 ? d1 : d2);
#pragma unroll
    for (int i = 0; i < 4; i++)
        tile[ty + 8 * i][tx] = ip[(r0 + ty + 8 * i) * 2048 + c0 + tx];
    __syncthreads();
#pragma unroll
    for (int i = 0; i < 4; i++)
        op[(c0 + ty + 8 * i) * 2048 + r0 + tx] = f2bf(tile[tx][ty + 8 * i]);
}

// ---------------- generic transpose + cast: in fp32 [R][C] (+z*ibs) -> out bf16 [C][R] (+z*obs) ----
__global__ __launch_bounds__(256) void k_tcast(const float* __restrict__ in, u16* __restrict__ out,
                                               int R, int C, long ibs, long obs) {
    __shared__ float tile[32][33];
    const int t = threadIdx.x;
    const int tx = t & 31, ty = t >> 5;
    const long r0 = (long)blockIdx.y * 32, c0 = (long)blockIdx.x * 32;
    const float* ip = in + (long)blockIdx.z * ibs;
    u16* op = out + (long)blockIdx.z * obs;
#pragma unroll
    for (int i = 0; i < 4; i++)
        tile[ty + 8 * i][tx] = ip[(r0 + ty + 8 * i) * C + c0 + tx];
    __syncthreads();
#pragma unroll
    for (int i = 0; i < 4; i++)
        op[(c0 + ty + 8 * i) * R + r0 + tx] = f2bf(tile[tx][ty + 8 * i]);
}

// ---------------- transpose bf16 -> bf16: in [R][C] (+z*ibs) -> out [C][R] (+z*obs) ----------------
__global__ __launch_bounds__(256) void k_tcast_bf(const u16* __restrict__ in, u16* __restrict__ out,
                                                  int R, int C, long ibs, long obs) {
    __shared__ u16 tile[32][34];
    const int t = threadIdx.x;
    const int tx = t & 31, ty = t >> 5;
    const long r0 = (long)blockIdx.y * 32, c0 = (long)blockIdx.x * 32;
    const u16* ip = in + (long)blockIdx.z * ibs;
    u16* op = out + (long)blockIdx.z * obs;
#pragma unroll
    for (int i = 0; i < 4; i++)
        tile[ty + 8 * i][tx] = ip[(r0 + ty + 8 * i) * C + c0 + tx];
    __syncthreads();
#pragma unroll
    for (int i = 0; i < 4; i++)
        op[(c0 + ty + 8 * i) * R + r0 + tx] = tile[tx][ty + 8 * i];
}

// ---------------- old 128x128 GEMM body (kept for the small y-GEMMs) ----------------
__device__ __forceinline__ void gemm_body(const u16* __restrict__ A, const u16* __restrict__ Bt,
                                          float* __restrict__ C, int N, int K) {
    __shared__ u16 As[128 * 32];
    __shared__ u16 Bs[128 * 32];
    const int t = threadIdx.x;
    const int lane = t & 63, wave = t >> 6;
    const long m0 = (long)blockIdx.y * 128, n0 = (long)blockIdx.x * 128;
    const int wm = (wave >> 1) * 64, wn = (wave & 1) * 64;
    const u16* Ag = A + (m0 + (t >> 2)) * (long)K + (t & 3) * 8;
    const u16* Bg = Bt + (n0 + (t >> 2)) * (long)K + (t & 3) * 8;
    u16* lA = As + wave * 512;
    u16* lB = Bs + wave * 512;
    const int fr = lane & 15, fg = (lane >> 4) * 8;
    const f32x4 z = {0.f, 0.f, 0.f, 0.f};
    f32x4 acc[4][4];
#pragma unroll
    for (int i = 0; i < 4; i++)
#pragma unroll
        for (int j = 0; j < 4; j++) acc[i][j] = z;
    for (int k0 = 0; k0 < K; k0 += 32) {
        __syncthreads();
        GLOAD16(Ag + k0, lA);
        GLOAD16(Ag + (long)64 * K + k0, lA + 2048);
        GLOAD16(Bg + k0, lB);
        GLOAD16(Bg + (long)64 * K + k0, lB + 2048);
        __syncthreads();
        short8 af[4], bfv[4];
#pragma unroll
        for (int i = 0; i < 4; i++) {
            af[i] = *(const short8*)&As[(wm + i * 16 + fr) * 32 + fg];
            bfv[i] = *(const short8*)&Bs[(wn + i * 16 + fr) * 32 + fg];
        }
#pragma unroll
        for (int i = 0; i < 4; i++)
#pragma unroll
            for (int j = 0; j < 4; j++)
                acc[i][j] = MFMA_16x16x32(af[i], bfv[j], acc[i][j]);
    }
    const int cr = (lane >> 4) * 4, cc = lane & 15;
#pragma unroll
    for (int i = 0; i < 4; i++)
#pragma unroll
        for (int j = 0; j < 4; j++)
#pragma unroll
            for (int r = 0; r < 4; r++)
                C[(m0 + wm + i * 16 + cr + r) * N + (n0 + wn + j * 16 + cc)] = acc[i][j][r];
}

__global__ __launch_bounds__(256) void k_gemm2(const u16* __restrict__ A,
                                               const u16* __restrict__ Bt0, const u16* __restrict__ Bt1,
                                               float* __restrict__ C0, float* __restrict__ C1,
                                               int N, int K) {
    gemm_body(A, blockIdx.z ? Bt1 : Bt0, blockIdx.z ? C1 : C0, N, K);
}

// ---------------- 256x256 / BK=64 / 8-wave phase-interleaved GEMM (8-phase template) -------------
// N segments of 2048 route B + output: seg0 fp32, seg1/2 bf16. LDS 128 KB dbuf.
// Swizzle: LDS 16B-slot ^= (row&7); inverse applied on per-lane global source (gload dest linear).
__global__ __launch_bounds__(512) void k_gemm_big(const u16* __restrict__ A,
                                                  const u16* __restrict__ Bq, const u16* __restrict__ Bk,
                                                  const u16* __restrict__ Bv,
                                                  float* __restrict__ Cq, u16* __restrict__ Ck,
                                                  u16* __restrict__ Cv, int K) {
    __shared__ u16 As[2][2][128 * 64];
    __shared__ u16 Bs[2][2][128 * 64];
    const int t = threadIdx.x, lane = t & 63, w = t >> 6;
    const long m0 = (long)blockIdx.y * 256;
    const int n0 = blockIdx.x * 256;
    const int seg = n0 >> 11, ncol = n0 & 2047;
    const u16* Bt = (seg == 0) ? Bq : ((seg == 1) ? Bk : Bv);
    const int wmh = w >> 2;            // A half this wave computes
    const int wn = (w & 3) * 64;       // N offset within 256
    const int bhalf = (w & 3) >> 1;    // B half
    const int rB0 = wn & 64;           // row base within B half
    const int fr = lane & 15, g = lane >> 4;
    const int f7 = fr & 7;
    const int ks0 = ((g ^ f7)) * 8;    // kk=0 swizzled slot offset (u16)
    const int ks1 = ks0 ^ 32;          // kk=1
    // staging per-lane constants
    const int sr = lane >> 3;                 // row sub-offset 0..7
    const int s8 = ((lane & 7) ^ sr) * 8;     // inverse-swizzled source slot (u16)
    const u16* Ag = A + m0 * (long)K;
    const u16* Bg = Bt + (long)ncol * K;

    const f32x4 z = {0.f, 0.f, 0.f, 0.f};
    f32x4 acc[8][4];
#pragma unroll
    for (int i = 0; i < 8; i++)
#pragma unroll
        for (int j = 0; j < 4; j++) acc[i][j] = z;

    auto stageA = [&](int buf, int kt) {
#pragma unroll
        for (int h = 0; h < 2; h++)
#pragma unroll
            for (int q = 0; q < 2; q++) {
                const int r = h * 128 + q * 64 + w * 8 + sr;
                GLOAD16(Ag + (long)r * K + kt * 64 + s8, &As[buf][h][(q * 512 + w * 64) * 8]);
            }
    };
    auto stageB = [&](int buf, int kt) {
#pragma unroll
        for (int h = 0; h < 2; h++)
#pragma unroll
            for (int q = 0; q < 2; q++) {
                const int r = h * 128 + q * 64 + w * 8 + sr;
                GLOAD16(Bg + (long)r * K + kt * 64 + s8, &Bs[buf][h][(q * 512 + w * 64) * 8]);
            }
    };

    // prologue: stage tile 0
    stageA(0, 0);
    stageB(0, 0);
    asm volatile("s_waitcnt vmcnt(0)" ::: "memory");
    __builtin_amdgcn_s_barrier();

    const int NT = K >> 6;
    for (int kt = 0; kt < NT; ++kt) {
        const int c = kt & 1;
        const bool pre = (kt + 1 < NT);
        short8 pa[4], pb[4];
        // ---- phase 0: A rows 0..63 @kk0 + B @kk0 ; stage next A ----
#pragma unroll
        for (int i = 0; i < 4; i++) pa[i] = *(const short8*)&As[c][wmh][(i * 16 + fr) * 64 + ks0];
#pragma unroll
        for (int j = 0; j < 4; j++) pb[j] = *(const short8*)&Bs[c][bhalf][(rB0 + j * 16 + fr) * 64 + ks0];
        if (pre) stageA(c ^ 1, kt + 1);
        __builtin_amdgcn_s_barrier();
        __builtin_amdgcn_s_setprio(1);
#pragma unroll
        for (int i = 0; i < 4; i++)
#pragma unroll
            for (int j = 0; j < 4; j++) acc[i][j] = MFMA_16x16x32(pa[i], pb[j], acc[i][j]);
        __builtin_amdgcn_s_setprio(0);
        __builtin_amdgcn_s_barrier();
        // ---- phase 1: A rows 64..127 @kk0 ; stage next B ----
#pragma unroll
        for (int i = 0; i < 4; i++) pa[i] = *(const short8*)&As[c][wmh][((i + 4) * 16 + fr) * 64 + ks0];
        if (pre) stageB(c ^ 1, kt + 1);
        __builtin_amdgcn_s_barrier();
        __builtin_amdgcn_s_setprio(1);
#pragma unroll
        for (int i = 0; i < 4; i++)
#pragma unroll
            for (int j = 0; j < 4; j++) acc[i + 4][j] = MFMA_16x16x32(pa[i], pb[j], acc[i + 4][j]);
        __builtin_amdgcn_s_setprio(0);
        __builtin_amdgcn_s_barrier();
        // ---- phase 2: A rows 0..63 @kk1 + B @kk1 ----
#pragma unroll
        for (int i = 0; i < 4; i++) pa[i] = *(const short8*)&As[c][wmh][(i * 16 + fr) * 64 + ks1];
#pragma unroll
        for (int j = 0; j < 4; j++) pb[j] = *(const short8*)&Bs[c][bhalf][(rB0 + j * 16 + fr) * 64 + ks1];
        __builtin_amdgcn_s_barrier();
        __builtin_amdgcn_s_setprio(1);
#pragma unroll
        for (int i = 0; i < 4; i++)
#pragma unroll
            for (int j = 0; j < 4; j++) acc[i][j] = MFMA_16x16x32(pa[i], pb[j], acc[i][j]);
        __builtin_amdgcn_s_setprio(0);
        __builtin_amdgcn_s_barrier();
        // ---- phase 3: A rows 64..127 @kk1 ; drain next-tile staging ----
#pragma unroll
        for (int i = 0; i < 4; i++) pa[i] = *(const short8*)&As[c][wmh][((i + 4) * 16 + fr) * 64 + ks1];
        asm volatile("s_waitcnt vmcnt(0)" ::: "memory");
        __builtin_amdgcn_s_barrier();
        __builtin_amdgcn_s_setprio(1);
#pragma unroll
        for (int i = 0; i < 4; i++)
#pragma unroll
            for (int j = 0; j < 4; j++) acc[i + 4][j] = MFMA_16x16x32(pa[i], pb[j], acc[i + 4][j]);
        __builtin_amdgcn_s_setprio(0);
        __builtin_amdgcn_s_barrier();
    }

    // epilogue
    const int cr = g * 4, cc = fr;
    if (seg == 0) {
#pragma unroll
        for (int ii = 0; ii < 8; ii++)
#pragma unroll
            for (int j = 0; j < 4; j++)
#pragma unroll
                for (int r = 0; r < 4; r++)
                    Cq[(m0 + wmh * 128 + ii * 16 + cr + r) * 2048 + (ncol + wn + j * 16 + cc)] = acc[ii][j][r];
    } else {
        u16* Co = (seg == 1) ? Ck : Cv;
#pragma unroll
        for (int ii = 0; ii < 8; ii++)
#pragma unroll
            for (int j = 0; j < 4; j++)
#pragma unroll
                for (int r = 0; r < 4; r++)
                    Co[(m0 + wmh * 128 + ii * 16 + cr + r) * 2048 + (ncol + wn + j * 16 + cc)] = f2bf(acc[ii][j][r]);
    }
}

// ---------------- LayerNorm over 2048 cols (+ optional RoPE) -> bf16 [B,H,Srows,128] ----------------
__device__ __forceinline__ void ln_core(float nv[8], const float* __restrict__ w,
                                        const float* __restrict__ bia, const float* __restrict__ freqs,
                                        u16* __restrict__ out, int bi, int s, int Srows,
                                        float eps, int do_rope, int t) {
    float sum = 0.f, sq = 0.f;
#pragma unroll
    for (int r = 0; r < 8; r++) { sum += nv[r]; sq += nv[r] * nv[r]; }
#pragma unroll
    for (int off = 32; off >= 1; off >>= 1) {
        sum += __shfl_xor(sum, off);
        sq += __shfl_xor(sq, off);
    }
    __shared__ float red[8];
    const int wv = t >> 6, lane = t & 63;
    if (lane == 0) { red[wv] = sum; red[4 + wv] = sq; }
    __syncthreads();
    sum = red[0] + red[1] + red[2] + red[3];
    sq  = red[4] + red[5] + red[6] + red[7];
    const float mu = sum * (1.f / 2048.f);
    const float rstd = rsqrtf(sq * (1.f / 2048.f) - mu * mu + eps);
    const int c0 = t * 8;
    f32x4 w0 = *(const f32x4*)(w + c0), w1 = *(const f32x4*)(w + c0 + 4);
    f32x4 b0 = *(const f32x4*)(bia + c0), b1 = *(const f32x4*)(bia + c0 + 4);
#pragma unroll
    for (int r = 0; r < 4; r++) {
        nv[r]     = (nv[r] - mu) * rstd * w0[r] + b0[r];
        nv[4 + r] = (nv[4 + r] - mu) * rstd * w1[r] + b1[r];
    }
    if (do_rope) {
        const float* fp = freqs + ((long)s * 64 + ((c0 & 127) >> 1)) * 2;
        f32x4 f0 = *(const f32x4*)(fp), f1 = *(const f32x4*)(fp + 4);
        float t0, t1;
        t0 = nv[0]; t1 = nv[1]; nv[0] = t0 * f0[0] - t1 * f0[1]; nv[1] = t0 * f0[1] + t1 * f0[0];
        t0 = nv[2]; t1 = nv[3]; nv[2] = t0 * f0[2] - t1 * f0[3]; nv[3] = t0 * f0[3] + t1 * f0[2];
        t0 = nv[4]; t1 = nv[5]; nv[4] = t0 * f1[0] - t1 * f1[1]; nv[5] = t0 * f1[1] + t1 * f1[0];
        t0 = nv[6]; t1 = nv[7]; nv[6] = t0 * f1[2] - t1 * f1[3]; nv[7] = t0 * f1[3] + t1 * f1[2];
    }
    const int h = c0 >> 7;
    ushort8v o;
#pragma unroll
    for (int r = 0; r < 8; r++) o[r] = f2bf(nv[r]);
    *(ushort8v*)(out + (((long)bi * 16 + h) * Srows + s) * 128 + (c0 & 127)) = o;
}

__global__ __launch_bounds__(256) void k_ln(const float* __restrict__ in, const float* __restrict__ w,
                                            const float* __restrict__ bia, const float* __restrict__ freqs,
                                            u16* __restrict__ out, int Srows, float eps, int do_rope) {
    const int row = blockIdx.x;
    const int bi = row / Srows, s = row - bi * Srows;
    const int t = threadIdx.x;
    const long base = (long)row * 2048 + t * 8;
    f32x4 v0 = *(const f32x4*)(in + base);
    f32x4 v1 = *(const f32x4*)(in + base + 4);
    float nv[8] = {v0[0], v0[1], v0[2], v0[3], v1[0], v1[1], v1[2], v1[3]};
    ln_core(nv, w, bia, freqs, out, bi, s, Srows, eps, do_rope, t);
}

__global__ __launch_bounds__(256) void k_ln_bf(const u16* __restrict__ in, const float* __restrict__ w,
                                               const float* __restrict__ bia, const float* __restrict__ freqs,
                                               u16* __restrict__ out, int Srows, float eps, int do_rope) {
    const int row = blockIdx.x;
    const int bi = row / Srows, s = row - bi * Srows;
    const int t = threadIdx.x;
    ushort8v v = *(const ushort8v*)(in + (long)row * 2048 + t * 8);
    float nv[8];
#pragma unroll
    for (int r = 0; r < 8; r++) nv[r] = bf2f(v[r]);
    ln_core(nv, w, bia, freqs, out, bi, s, Srows, eps, do_rope, t);
}

// ---------------- fused dual flash attention (async dbuf, native-exp2 softmax, cvt_pk) ----------
__global__ __launch_bounds__(256, 4) void k_attn(const u16* __restrict__ Q, const u16* __restrict__ Kg,
                                                 const u16* __restrict__ Vt, const u16* __restrict__ Yk,
                                                 const u16* __restrict__ Yvt, const float* __restrict__ gate,
                                                 u16* __restrict__ Out) {
    __shared__ u16 Ks[2][32 * 128];
    __shared__ u16 Vs[2][128 * 32];
    __shared__ u16 Ps[4][16 * 40];
    const int t = threadIdx.x, lane = t & 63, wave = t >> 6;
    const int h = blockIdx.y, b = blockIdx.z;
    const int q0 = blockIdx.x * 64 + wave * 16;
    const long bh = (long)b * 16 + h;
    const int fr = lane & 15;
    const int g = lane >> 4;
    const int fg8 = g * 8;
    const float scale2 = 0.08838834764831845f * 1.4426950408889634f;
    const f32x4 z = {0.f, 0.f, 0.f, 0.f};

    const int kr0 = (wave * 2 + 0) * 4 + (lane >> 4);
    const int kr1 = (wave * 2 + 1) * 4 + (lane >> 4);
    const int kc0 = ((lane & 15) ^ (kr0 & 7)) * 8;
    const int kc1 = ((lane & 15) ^ (kr1 & 7)) * 8;
    const int vr0 = (wave * 2 + 0) * 16 + (lane >> 2);
    const int vr1 = (wave * 2 + 1) * 16 + (lane >> 2);
    const int vc = (lane & 3) * 8;

    const u16* qp = Q + (bh * 2048 + q0 + fr) * 128;
    short8 qf[4];
#pragma unroll
    for (int ks = 0; ks < 4; ks++) qf[ks] = *(const short8*)(qp + fg8 + ks * 32);

    f32x4 o1[8], o2[8];
    const int sw = (fr & 7) * 8;

    auto stage = [&](int buf, const u16* kp, const u16* vp, int kb, long vstride) {
        GLOAD16(kp + (long)(kb + kr0) * 128 + kc0, &Ks[buf][(wave * 2 + 0) * 512]);
        GLOAD16(kp + (long)(kb + kr1) * 128 + kc1, &Ks[buf][(wave * 2 + 1) * 512]);
        GLOAD16(vp + (long)vr0 * vstride + kb + vc, &Vs[buf][(wave * 2 + 0) * 512]);
        GLOAD16(vp + (long)vr1 * vstride + kb + vc, &Vs[buf][(wave * 2 + 1) * 512]);
    };

    auto flash = [&](const u16* kp, const u16* vp, int L, long vstride, f32x4* oout) {
        float m = -3.0e38f, l = 0.f;
        f32x4 oacc[8];
#pragma unroll
        for (int i = 0; i < 8; i++) oacc[i] = z;
        stage(0, kp, vp, 0, vstride);
        __syncthreads();
        const int nt = L / 32;
        for (int ti = 0; ti < nt; ti++) {
            const int cur = ti & 1;
            if (ti + 1 < nt) stage(cur ^ 1, kp, vp, (ti + 1) * 32, vstride);
            f32x4 c0 = z, c1 = z;
#pragma unroll
            for (int ks = 0; ks < 4; ks++) {
                short8 k0f = *(const short8*)&Ks[cur][fr * 128 + ((fg8 + ks * 32) ^ sw)];
                short8 k1f = *(const short8*)&Ks[cur][(16 + fr) * 128 + ((fg8 + ks * 32) ^ sw)];
                c0 = MFMA_16x16x32(k0f, qf[ks], c0);
                c1 = MFMA_16x16x32(k1f, qf[ks], c1);
            }
            float r0 = fmaxf(fmaxf(c0[0], c0[1]), fmaxf(c0[2], c0[3]));
            float r1 = fmaxf(fmaxf(c1[0], c1[1]), fmaxf(c1[2], c1[3]));
            float rmax = fmaxf(r0, r1);
            rmax = fmaxf(rmax, __shfl_xor(rmax, 16));
            rmax = fmaxf(rmax, __shfl_xor(rmax, 32));
            const float tmax = rmax * scale2;
            if (!__all(tmax <= m + 8.f)) {
                float mn = fmaxf(m, tmax);
                float corr = __builtin_amdgcn_exp2f(m - mn);
#pragma unroll
                for (int i = 0; i < 8; i++) oacc[i] *= corr;
                l *= corr;
                m = mn;
            }
            float p[8], ts = 0.f;
#pragma unroll
            for (int r = 0; r < 4; r++) {
                p[r]     = __builtin_amdgcn_exp2f(__builtin_fmaf(c0[r], scale2, -m));
                p[4 + r] = __builtin_amdgcn_exp2f(__builtin_fmaf(c1[r], scale2, -m));
            }
#pragma unroll
            for (int r = 0; r < 8; r++) ts += p[r];
            ts += __shfl_xor(ts, 16);
            ts += __shfl_xor(ts, 32);
            l += ts;
            uint2v w0, w1;
            w0[0] = cvtpk_bf16(p[0], p[1]); w0[1] = cvtpk_bf16(p[2], p[3]);
            w1[0] = cvtpk_bf16(p[4], p[5]); w1[1] = cvtpk_bf16(p[6], p[7]);
            *(uint2v*)&Ps[wave][fr * 40 + g * 4] = w0;
            *(uint2v*)&Ps[wave][fr * 40 + 16 + g * 4] = w1;
            short8 pf = *(const short8*)&Ps[wave][fr * 40 + fg8];
#pragma unroll
            for (int dt = 0; dt < 8; dt++) {
                short8 vf = *(const short8*)&Vs[cur][(dt * 16 + fr) * 32 + fg8];
                oacc[dt] = MFMA_16x16x32(vf, pf, oacc[dt]);
            }
            __syncthreads();
        }
        float inv = 1.f / l;
#pragma unroll
        for (int i = 0; i < 8; i++) oout[i] = oacc[i] * inv;
    };

    flash(Kg + bh * 2048 * 128, Vt + bh * 128 * 2048, 2048, 2048, o1);
    flash(Yk + bh * 512 * 128, Yvt + bh * 128 * 512, 512, 512, o2);

    const float tg = tanhf(gate[h]);
    u16* op = Out + ((long)b * 2048 + q0 + fr) * 2048 + h * 128;
#pragma unroll
    for (int dt = 0; dt < 8; dt++) {
        ushort4v w4;
#pragma unroll
        for (int r = 0; r < 4; r++) w4[r] = f2bf(o1[dt][r] + tg * o2[dt][r]);
        *(ushort4v*)(op + dt * 16 + g * 4) = w4;
    }
}

extern "C" void kernel_launch(void* const* d_in, const int* in_sizes, int n_in,
                              void* d_out, int out_size, void* d_ws, size_t ws_size,
                              hipStream_t stream) {
    (void)in_sizes; (void)n_in; (void)out_size; (void)ws_size;
    const float* x     = (const float*)d_in[0];
    const float* freqs = (const float*)d_in[2];
    const float* y     = (const float*)d_in[3];
    const float* wq    = (const float*)d_in[5];
    const float* wk    = (const float*)d_in[6];
    const float* wv    = (const float*)d_in[7];
    const float* wo    = (const float*)d_in[8];
    const float* wky   = (const float*)d_in[9];
    const float* wvy   = (const float*)d_in[10];
    const float* gate  = (const float*)d_in[11];
    const float* qn_w  = (const float*)d_in[12];
    const float* qn_b  = (const float*)d_in[13];
    const float* kn_w  = (const float*)d_in[14];
    const float* kn_b  = (const float*)d_in[15];
    const float* kyn_w = (const float*)d_in[16];
    const float* kyn_b = (const float*)d_in[17];
    float* out = (float*)d_out;

    char* p = (char*)d_ws;
    u16* xb   = (u16*)p; p += 4096L * 2048 * 2;
    u16* yb   = (u16*)p; p += 1024L * 2048 * 2;
    u16* wT   = (u16*)p; p += 2048L * 2048 * 2;  // wq^T / later wky^T / later wo^T
    u16* qb   = (u16*)p; p += 4096L * 2048 * 2;  // Q heads; earlier: wk^T
    u16* kbuf = (u16*)p; p += 4096L * 2048 * 2;  // K heads; earlier: wv^T
    u16* vtb  = (u16*)p; p += 4096L * 2048 * 2;  // V^T heads; earlier: K-raw bf16
    u16* ykb  = (u16*)p; p += 1024L * 2048 * 2;  // yK heads
    u16* yvtb = (u16*)p; p += 1024L * 2048 * 2;  // yV^T heads
    u16* aob  = (u16*)p; p += 4096L * 2048 * 2;  // attn out; earlier: V-raw bf16, yV-raw fp32
    float* raw = out;            // d_out doubles as fp32 scratch (4096x2048 fp32)
    u16* wTk   = qb;             // wk^T parking
    u16* wTv   = kbuf;           // wv^T parking
    u16* krawb = vtb;            // K GEMM bf16 out
    u16* vrawb = aob;            // V GEMM bf16 out
    u16* wT2   = ykb;            // wvy^T parking (spans ykb+yvtb)
    float* rawB = (float*)aob;   // yV GEMM fp32 out

    // input casts (merged)
    k_cast2<<<dim3(5120), dim3(256), 0, stream>>>(x, xb, y, yb, 4096);

    // merged QKV projection (3 weight transposes batched) — 256² 8-phase GEMM
    k_tcastB<<<dim3(64, 64, 3), dim3(256), 0, stream>>>(wq, wk, wv, wT, wTk, wTv);
    k_gemm_big<<<dim3(24, 16), dim3(512), 0, stream>>>(xb, wT, wTk, wTv, raw, krawb, vrawb, 2048);
    k_ln<<<dim3(4096), dim3(256), 0, stream>>>(raw, qn_w, qn_b, freqs, qb, 2048, 1e-5f, 1);
    k_ln_bf<<<dim3(4096), dim3(256), 0, stream>>>(krawb, kn_w, kn_b, freqs, kbuf, 2048, 1e-5f, 1);
    k_tcast_bf<<<dim3(64, 64, 2), dim3(256), 0, stream>>>(vrawb, vtb, 2048, 2048, 2048L * 2048, 2048L * 2048);

    // yK + yV paths (2 weight transposes batched), batched 128² GEMM (z=2)
    k_tcastB<<<dim3(64, 64, 2), dim3(256), 0, stream>>>(wky, wvy, wvy, wT, wT2, wT2);
    k_gemm2<<<dim3(16, 8, 2), dim3(256), 0, stream>>>(yb, wT, wT2, raw, rawB, 2048, 2048);
    k_ln<<<dim3(1024), dim3(256), 0, stream>>>(raw, kyn_w, kyn_b, freqs, ykb, 512, 1e-6f, 0);
    k_tcast<<<dim3(64, 16, 2), dim3(256), 0, stream>>>(rawB, yvtb, 512, 2048, 512L * 2048, 2048L * 512);

    // fused dual attention
    k_attn<<<dim3(32, 16, 2), dim3(256), 0, stream>>>(qb, kbuf, vtb, ykb, yvtb, gate, aob);

    // output projection — same 256² kernel, seg0 (fp32) path only
    k_tcastB<<<dim3(64, 64, 1), dim3(256), 0, stream>>>(wo, wo, wo, wT, wT, wT);
    k_gemm_big<<<dim3(8, 16), dim3(512), 0, stream>>>(aob, wT, wT, wT, out, krawb, krawb, 2048);
}